// Round 13
// baseline (1667.344 us; speedup 1.0000x reference)
//
#include <hip/hip_runtime.h>
#include <stdint.h>

typedef unsigned short u16;
typedef unsigned int   u32;

#define L_N  6
#define D_N  768
#define F_N  3072
#define H_N  12
#define B_N  2
#define S_N  2048
#define BS_N 4096   // B*S rows
#define QKV_N 2304  // fused q|k|v width
#define CSC  0.18033688011112042f   // 1/sqrt(64) * log2(e), folded into Q
#define DTHR 11.54f                 // 8 * log2(e): defer-max threshold (exp2 domain)
#define NQT  (S_N / 128)            // q-tiles per (b,h) = 16
#define NFLG (B_N * H_N * NQT)      // flags per layer = 384

using bf16x8 = __attribute__((ext_vector_type(8))) short;
using f32x4  = __attribute__((ext_vector_type(4))) float;
using f32x16 = __attribute__((ext_vector_type(16))) float;
using u32x2  = __attribute__((ext_vector_type(2))) unsigned int;

__device__ __forceinline__ u16 f2bf(float f) {
  u32 x = __builtin_bit_cast(u32, f);
  x += 0x7FFFu + ((x >> 16) & 1u);
  return (u16)(x >> 16);
}

__device__ __forceinline__ float bf2f(u16 v) {
  return __builtin_bit_cast(float, (u32)v << 16);
}

__device__ __forceinline__ u32 cvt_pk_bf16(float lo, float hi) {
  u32 r;
  asm("v_cvt_pk_bf16_f32 %0, %1, %2" : "=v"(r) : "v"(lo), "v"(hi));
  return r;
}

#define GLOAD16(g, l)                                                                     \
  __builtin_amdgcn_global_load_lds((const __attribute__((address_space(1))) void*)(g),    \
                                   (__attribute__((address_space(3))) void*)(l), 16, 0, 0)

// ---------- zero the merge flags (once per launch; handles poison + replay) ----------
__global__ __launch_bounds__(256) void zero_flags_kernel(u32* __restrict__ f, int n)
{
  const int i = blockIdx.x * 256 + threadIdx.x;
  if (i < n) f[i] = 0;
}

// ---------- transpose + cast: in (L,K,N) f32 -> out rows at (l*lstride + (rowoff+n)*K) bf16 ----------
__global__ __launch_bounds__(256) void transpose_cast_kernel(
    const float* __restrict__ in, u16* __restrict__ out, int K, int N,
    size_t out_lstride, int out_rowoff)
{
  __shared__ float tile[32][33];
  const int l  = blockIdx.z;
  const int n0 = blockIdx.x * 32, k0 = blockIdx.y * 32;
  const int tx = threadIdx.x & 31, ty = threadIdx.x >> 5;
  const float* src = in + (size_t)l * K * N;
  u16* dst = out + (size_t)l * out_lstride + (size_t)out_rowoff * K;
#pragma unroll
  for (int i = 0; i < 4; ++i)
    tile[ty + i * 8][tx] = src[(size_t)(k0 + ty + i * 8) * N + n0 + tx];
  __syncthreads();
#pragma unroll
  for (int i = 0; i < 4; ++i)
    dst[(size_t)(n0 + ty + i * 8) * K + k0 + tx] = f2bf(tile[tx][ty + i * 8]);
}

// ---------- concat q|k|v biases into (L, 2304) ----------
__global__ __launch_bounds__(256) void concat_bias_kernel(
    const float* __restrict__ bq, const float* __restrict__ bk,
    const float* __restrict__ bv, float* __restrict__ out)
{
  const int i = blockIdx.x * 256 + threadIdx.x;   // exact grid: L*2304
  const int l = i / QKV_N, c = i - l * QKV_N;
  float v = (c < 768) ? bq[l * 768 + c]
          : (c < 1536) ? bk[l * 768 + c - 768]
                       : bv[l * 768 + c - 1536];
  out[i] = v;
}

// ---------- LayerNorm: one row (768) per block; input fp32 or bf16 ----------
template<bool BF16IN>
__global__ __launch_bounds__(256) void ln_kernel(
    const void* __restrict__ xv, const float* __restrict__ w, const float* __restrict__ b,
    float* __restrict__ outF, u16* __restrict__ outB)
{
  const int row = blockIdx.x, tid = threadIdx.x;
  float v[3];
  float s = 0.f;
  if (BF16IN) {
    const u16* xr = (const u16*)xv + (size_t)row * D_N;
#pragma unroll
    for (int i = 0; i < 3; ++i) { v[i] = bf2f(xr[tid + i * 256]); s += v[i]; }
  } else {
    const float* xr = (const float*)xv + (size_t)row * D_N;
#pragma unroll
    for (int i = 0; i < 3; ++i) { v[i] = xr[tid + i * 256]; s += v[i]; }
  }
  __shared__ float red[8];
  const int wave = tid >> 6, lane = tid & 63;
#pragma unroll
  for (int o = 32; o > 0; o >>= 1) s += __shfl_down(s, o, 64);
  if (lane == 0) red[wave] = s;
  __syncthreads();
  const float mu = (red[0] + red[1] + red[2] + red[3]) * (1.f / D_N);
  float d2 = 0.f;
#pragma unroll
  for (int i = 0; i < 3; ++i) { float d = v[i] - mu; d2 += d * d; }
#pragma unroll
  for (int o = 32; o > 0; o >>= 1) d2 += __shfl_down(d2, o, 64);
  if (lane == 0) red[4 + wave] = d2;
  __syncthreads();
  const float var = (red[4] + red[5] + red[6] + red[7]) * (1.f / D_N);
  const float rs = rsqrtf(var + 1e-5f);
#pragma unroll
  for (int i = 0; i < 3; ++i) {
    const int c = tid + i * 256;
    const float o = (v[i] - mu) * rs * w[c] + b[c];
    if (outF) outF[(size_t)row * D_N + c] = o;
    if (outB) outB[(size_t)row * D_N + c] = f2bf(o);
  }
}

// ---------- GEMM 128x128: C = A @ Wt^T + bias, fused epilogue (QKV / W1) ----------
template<bool GELU, bool OUTB, bool SCALEQ>
__global__ __launch_bounds__(256) void gemm_kernel(
    const u16* __restrict__ A, const u16* __restrict__ Wt,
    const float* __restrict__ bias,
    u16* __restrict__ outB, int M, int N, int K)
{
  __shared__ __align__(16) u16 As[2][128 * 32];
  __shared__ __align__(16) u16 Bs[2][128 * 32];
  const int tid  = threadIdx.x;
  const int wave = tid >> 6, lane = tid & 63;
  const int lr = lane & 15, lg = lane >> 4;
  const int row0 = blockIdx.x * 128, col0 = blockIdx.y * 128;
  const int wr = (wave >> 1) * 64, wc = (wave & 1) * 64;

  const int cb0 = wave * 64;
  const int cb1 = 256 + wave * 64;
  const int r0s = (cb0 + lane) >> 2, c0s = ((cb0 + lane) & 3) << 3;
  const int r1s = (cb1 + lane) >> 2, c1s = ((cb1 + lane) & 3) << 3;

  f32x4 acc[4][4] = {};

#define STAGE(cbuf, kk)                                                           \
  do {                                                                            \
    GLOAD16(A  + (size_t)(row0 + r0s) * K + (kk) + c0s, &As[cbuf][cb0 * 8]);      \
    GLOAD16(Wt + (size_t)(col0 + r0s) * K + (kk) + c0s, &Bs[cbuf][cb0 * 8]);      \
    GLOAD16(A  + (size_t)(row0 + r1s) * K + (kk) + c1s, &As[cbuf][cb1 * 8]);      \
    GLOAD16(Wt + (size_t)(col0 + r1s) * K + (kk) + c1s, &Bs[cbuf][cb1 * 8]);      \
  } while (0)

  STAGE(0, 0);
  __syncthreads();

  int c = 0;
  for (int k0 = 0; k0 < K; k0 += 32, c ^= 1) {
    if (k0 + 32 < K) STAGE(c ^ 1, k0 + 32);
    bf16x8 af[4], bfr[4];
#pragma unroll
    for (int m = 0; m < 4; ++m)
      af[m] = *(const bf16x8*)&As[c][(wr + m * 16 + lr) * 32 + lg * 8];
#pragma unroll
    for (int n = 0; n < 4; ++n)
      bfr[n] = *(const bf16x8*)&Bs[c][(wc + n * 16 + lr) * 32 + lg * 8];
    __builtin_amdgcn_s_setprio(1);
#pragma unroll
    for (int m = 0; m < 4; ++m)
#pragma unroll
      for (int n = 0; n < 4; ++n)
        acc[m][n] = __builtin_amdgcn_mfma_f32_16x16x32_bf16(af[m], bfr[n], acc[m][n], 0, 0, 0);
    __builtin_amdgcn_s_setprio(0);
    __syncthreads();
  }
#undef STAGE

#pragma unroll
  for (int m = 0; m < 4; ++m)
#pragma unroll
    for (int n = 0; n < 4; ++n) {
      const int col = col0 + wc + n * 16 + lr;
      const float bv = bias[col];
#pragma unroll
      for (int r = 0; r < 4; ++r) {
        const int row = row0 + wr + m * 16 + lg * 4 + r;
        float v = acc[m][n][r] + bv;
        if (GELU) v = 0.5f * v * (1.f + erff(v * 0.70710678118f));
        if (SCALEQ && col < 768) v *= CSC;   // fold softmax scale into q
        const size_t idx = (size_t)row * N + col;
        if (OUTB) outB[idx] = f2bf(v);
      }
    }
}

// ---------- GEMM 64x64 (Wo, W2): +bias +bf16resid -> bf16 out ----------
__global__ __launch_bounds__(256) void gemm64_kernel(
    const u16* __restrict__ A, const u16* __restrict__ Wt,
    const float* __restrict__ bias, const u16* __restrict__ resid,
    u16* __restrict__ outB, int M, int N, int K)
{
  __shared__ __align__(16) u16 As[2][64 * 32];
  __shared__ __align__(16) u16 Bs[2][64 * 32];
  const int tid  = threadIdx.x;
  const int wave = tid >> 6, lane = tid & 63;
  const int lr = lane & 15, lg = lane >> 4;
  const int row0 = blockIdx.x * 64, col0 = blockIdx.y * 64;
  const int wr = (wave >> 1) * 32, wc = (wave & 1) * 32;

  const int cb = wave * 64;
  const int ch = cb + lane;
  const int rs = ch >> 2, cs = (ch & 3) << 3;

  f32x4 acc[2][2] = {};

#define STAGE64(cbuf, kk)                                                         \
  do {                                                                            \
    GLOAD16(A  + (size_t)(row0 + rs) * K + (kk) + cs, &As[cbuf][cb * 8]);         \
    GLOAD16(Wt + (size_t)(col0 + rs) * K + (kk) + cs, &Bs[cbuf][cb * 8]);         \
  } while (0)

  STAGE64(0, 0);
  __syncthreads();

  int c = 0;
  for (int k0 = 0; k0 < K; k0 += 32, c ^= 1) {
    if (k0 + 32 < K) STAGE64(c ^ 1, k0 + 32);
    bf16x8 af[2], bfr[2];
#pragma unroll
    for (int m = 0; m < 2; ++m)
      af[m] = *(const bf16x8*)&As[c][(wr + m * 16 + lr) * 32 + lg * 8];
#pragma unroll
    for (int n = 0; n < 2; ++n)
      bfr[n] = *(const bf16x8*)&Bs[c][(wc + n * 16 + lr) * 32 + lg * 8];
    __builtin_amdgcn_s_setprio(1);
#pragma unroll
    for (int m = 0; m < 2; ++m)
#pragma unroll
      for (int n = 0; n < 2; ++n)
        acc[m][n] = __builtin_amdgcn_mfma_f32_16x16x32_bf16(af[m], bfr[n], acc[m][n], 0, 0, 0);
    __builtin_amdgcn_s_setprio(0);
    __syncthreads();
  }
#undef STAGE64

#pragma unroll
  for (int m = 0; m < 2; ++m)
#pragma unroll
    for (int n = 0; n < 2; ++n) {
      const int col = col0 + wc + n * 16 + lr;
      const float bv = bias[col];
#pragma unroll
      for (int r = 0; r < 4; ++r) {
        const int row = row0 + wr + m * 16 + lg * 4 + r;
        const size_t idx = (size_t)row * N + col;
        outB[idx] = f2bf(acc[m][n][r] + bv + bf2f(resid[idx]));
      }
    }
}

// ---------- Flash attention v13: v12 + tree reductions + in-kernel merge ----------
// 32x32x16 MFMA, 4 waves x 32 q = 128 q/block; KVBLK=64, T14 issue-early.
// blockIdx.z selects KV half. Each block writes fp32 partial (unnormalized O,
// m, l); LAST arriver (device-scope atomic handshake) merges both halves from
// memory in fixed z-order (deterministic) and writes bf16 ab directly.
__global__ __launch_bounds__(256) void attn_kernel(
    const u16* __restrict__ QKV, float* __restrict__ Opart, float* __restrict__ Ml,
    u16* __restrict__ O, u32* __restrict__ flags)
{
  constexpr int LDQ = QKV_N;
  constexpr int NT  = S_N / 64;   // 32
  constexpr int BH  = B_N * H_N;
  __shared__ __align__(16) u16 Ks [64 * 72];   // [key][dh]
  __shared__ __align__(16) u16 VTs[64 * 72];   // [dh][key]
  const int tid  = threadIdx.x;
  const int wave = tid >> 6, lane = tid & 63;
  const int l31 = lane & 31, l5 = lane >> 5;
  const int bh = blockIdx.y;
  const int b = bh / H_N, h = bh - b * H_N;
  const int q0 = blockIdx.x * 128;
  const int z  = blockIdx.z;
  const int t0 = z * (NT / 2), t1 = (z + 1) * (NT / 2);
  const size_t rowbase = (size_t)b * S_N * LDQ;
  const u16* Qg = QKV + rowbase + h * 64;
  const u16* Kg = QKV + rowbase + 768 + h * 64;
  const u16* Vg = QKV + rowbase + 1536 + h * 64;

  const int qrow = q0 + wave * 32 + l31;
  bf16x8 qf[4];
#pragma unroll
  for (int ks = 0; ks < 4; ++ks)
    qf[ks] = *(const bf16x8*)(Qg + (size_t)qrow * LDQ + ks * 16 + l5 * 8);

  f32x16 o0 = {}, o1 = {};
  float m = -1e30f, l = 0.f;

  const int kr = tid >> 2, kc = (tid & 3) * 16;   // K staging coords
  const int pp = tid >> 3, cg = tid & 7;          // V staging coords

  const u16* gk0 = Kg + (size_t)(t0 * 64 + kr) * LDQ + kc;
  const u16* gv0 = Vg + (size_t)(t0 * 64 + 2 * pp) * LDQ + cg * 8;
  uint4 nk0 = *(const uint4*)gk0, nk1 = *(const uint4*)(gk0 + 8);
  uint4 nv0 = *(const uint4*)gv0, nv1 = *(const uint4*)(gv0 + LDQ);

  for (int t = t0; t < t1; ++t) {
    __syncthreads();
    { // LDS writes of tile t (K row-major; V transposed, jj-rotated u32 pairs)
      *(uint4*)&Ks[kr * 72 + kc]     = nk0;
      *(uint4*)&Ks[kr * 72 + kc + 8] = nk1;
      const u16* a0 = (const u16*)&nv0;
      const u16* a1 = (const u16*)&nv1;
#pragma unroll
      for (int j = 0; j < 8; ++j) {
        const int jj = (j + cg) & 7;
        *(u32*)&VTs[(cg * 8 + jj) * 72 + 2 * pp] = (u32)a0[jj] | ((u32)a1[jj] << 16);
      }
    }
    __syncthreads();

    if (t + 1 < t1) {
      const u16* gk1 = Kg + (size_t)((t + 1) * 64 + kr) * LDQ + kc;
      const u16* gv1 = Vg + (size_t)((t + 1) * 64 + 2 * pp) * LDQ + cg * 8;
      nk0 = *(const uint4*)gk1; nk1 = *(const uint4*)(gk1 + 8);
      nv0 = *(const uint4*)gv1; nv1 = *(const uint4*)(gv1 + LDQ);
    }

    // S^T = K @ Q^T: sv0/sv1 cover keys 0..31 / 32..63 x q=l31
    f32x16 sv0 = {}, sv1 = {};
    __builtin_amdgcn_s_setprio(1);
#pragma unroll
    for (int ks = 0; ks < 4; ++ks) {
      const bf16x8 kf0 = *(const bf16x8*)&Ks[(l31)      * 72 + ks * 16 + l5 * 8];
      const bf16x8 kf1 = *(const bf16x8*)&Ks[(32 + l31) * 72 + ks * 16 + l5 * 8];
      sv0 = __builtin_amdgcn_mfma_f32_32x32x16_bf16(kf0, qf[ks], sv0, 0, 0, 0);
      sv1 = __builtin_amdgcn_mfma_f32_32x32x16_bf16(kf1, qf[ks], sv1, 0, 0, 0);
    }
    __builtin_amdgcn_s_setprio(0);

    // online softmax; TREE max (depth ~6 vs serial 31-chain)
    float t8[8];
#pragma unroll
    for (int i = 0; i < 8; ++i)
      t8[i] = fmaxf(fmaxf(sv0[i], sv0[i + 8]), fmaxf(sv1[i], sv1[i + 8]));
#pragma unroll
    for (int i = 0; i < 4; ++i) t8[i] = fmaxf(t8[i], t8[i + 4]);
    float mx = fmaxf(fmaxf(t8[0], t8[2]), fmaxf(t8[1], t8[3]));
    {
      const u32 mb = __builtin_bit_cast(u32, mx);
      const u32x2 rr = __builtin_amdgcn_permlane32_swap(mb, mb, false, false);
      mx = fmaxf(__builtin_bit_cast(float, rr[0]), __builtin_bit_cast(float, rr[1]));
    }
    if (!__all(mx - m <= DTHR)) {
      const float mn = fmaxf(m, mx);
      const float al = __builtin_amdgcn_exp2f(m - mn);
      m = mn;
      l *= al;
#pragma unroll
      for (int i = 0; i < 16; ++i) { o0[i] *= al; o1[i] *= al; }
    }
#pragma unroll
    for (int i = 0; i < 16; ++i) sv0[i] = __builtin_amdgcn_exp2f(sv0[i] - m);
#pragma unroll
    for (int i = 0; i < 16; ++i) sv1[i] = __builtin_amdgcn_exp2f(sv1[i] - m);
    // TREE sum
    float s8[8];
#pragma unroll
    for (int i = 0; i < 8; ++i)
      s8[i] = (sv0[i] + sv0[i + 8]) + (sv1[i] + sv1[i + 8]);
#pragma unroll
    for (int i = 0; i < 4; ++i) s8[i] += s8[i + 4];
    float rs = (s8[0] + s8[2]) + (s8[1] + s8[3]);
    {
      const u32 sb = __builtin_bit_cast(u32, rs);
      const u32x2 rr = __builtin_amdgcn_permlane32_swap(sb, sb, false, false);
      rs = __builtin_bit_cast(float, rr[0]) + __builtin_bit_cast(float, rr[1]);
    }
    l += rs;

    // P -> bf16 B-fragments in-register (T12)
    bf16x8 pb[4];
#pragma unroll
    for (int kb = 0; kb < 2; ++kb) {
      const f32x16& p = kb ? sv1 : sv0;
#pragma unroll
      for (int half = 0; half < 2; ++half) {
        const int o8 = half * 8;
        const u32 a0 = cvt_pk_bf16(p[o8 + 0], p[o8 + 1]);
        const u32 b0 = cvt_pk_bf16(p[o8 + 4], p[o8 + 5]);
        const u32 a1 = cvt_pk_bf16(p[o8 + 2], p[o8 + 3]);
        const u32 b1 = cvt_pk_bf16(p[o8 + 6], p[o8 + 7]);
        const u32x2 r0 = __builtin_amdgcn_permlane32_swap(a0, b0, false, false);
        const u32x2 r1 = __builtin_amdgcn_permlane32_swap(a1, b1, false, false);
        u32 w[4] = { r0[0], r1[0], r0[1], r1[1] };
        pb[kb * 2 + half] = __builtin_bit_cast(bf16x8, *(const uint4*)w);
      }
    }

    // PV
    __builtin_amdgcn_s_setprio(1);
#pragma unroll
    for (int ks2 = 0; ks2 < 4; ++ks2) {
      const bf16x8 vf0 = *(const bf16x8*)&VTs[(l31)      * 72 + ks2 * 16 + l5 * 8];
      const bf16x8 vf1 = *(const bf16x8*)&VTs[(32 + l31) * 72 + ks2 * 16 + l5 * 8];
      o0 = __builtin_amdgcn_mfma_f32_32x32x16_bf16(vf0, pb[ks2], o0, 0, 0, 0);
      o1 = __builtin_amdgcn_mfma_f32_32x32x16_bf16(vf1, pb[ks2], o1, 0, 0, 0);
    }
    __builtin_amdgcn_s_setprio(0);
  }

  // ---- write this half's partial (unnormalized fp32 O + m, l) ----
  float* op = Opart + (((size_t)z * BH + bh) * S_N + qrow) * 64;
#pragma unroll
  for (int r = 0; r < 16; r += 2) {
    const int dh = (r & 3) + 8 * (r >> 2) + 4 * l5;
    *(float2*)(op + dh)      = float2{o0[r], o0[r + 1]};
    *(float2*)(op + dh + 32) = float2{o1[r], o1[r + 1]};
  }
  if (l5 == 0) {
    float* mlp = Ml + (((size_t)z * BH + bh) * S_N + qrow) * 2;
    mlp[0] = m; mlp[1] = l;
  }

  // ---- device-scope handshake: last arriver merges ----
  __shared__ int s_last;
  __syncthreads();                 // all partial stores drained before barrier
  if (tid == 0) {
    __threadfence();               // release: partials device-visible
    const u32 old = atomicAdd(&flags[bh * NQT + blockIdx.x], 1u);
    __threadfence();               // acquire for merge reads
    s_last = (old == 1u);
  }
  __syncthreads();
  if (!s_last) return;

  // merge both halves from memory, fixed z-order -> deterministic
  const float* P0 = Opart + (((size_t)0 * BH + bh) * S_N + q0) * 64;
  const float* P1 = Opart + (((size_t)1 * BH + bh) * S_N + q0) * 64;
  const float* M0 = Ml + (((size_t)0 * BH + bh) * S_N + q0) * 2;
  const float* M1 = Ml + (((size_t)1 * BH + bh) * S_N + q0) * 2;
  const int rr = tid >> 1, cc = (tid & 1) * 32;    // row 0..127, col half
  const float m0 = M0[rr * 2], l0 = M0[rr * 2 + 1];
  const float m1 = M1[rr * 2], l1 = M1[rr * 2 + 1];
  const float mm = fmaxf(m0, m1);
  const float a0 = __builtin_amdgcn_exp2f(m0 - mm);
  const float a1 = __builtin_amdgcn_exp2f(m1 - mm);
  const float inv = 1.f / (a0 * l0 + a1 * l1);
  const float* r0p = P0 + rr * 64 + cc;
  const float* r1p = P1 + rr * 64 + cc;
  u16* orow = O + (size_t)(b * S_N + q0 + rr) * D_N + h * 64 + cc;
#pragma unroll
  for (int j = 0; j < 32; j += 2) {
    const float x0 = (a0 * r0p[j]     + a1 * r1p[j])     * inv;
    const float x1 = (a0 * r0p[j + 1] + a1 * r1p[j + 1]) * inv;
    *(u32*)(orow + j) = cvt_pk_bf16(x0, x1);
  }
}

// ---------- orchestration ----------
extern "C" void kernel_launch(void* const* d_in, const int* in_sizes, int n_in,
                              void* d_out, int out_size, void* d_ws, size_t ws_size,
                              hipStream_t stream)
{
  (void)in_sizes; (void)n_in; (void)out_size; (void)ws_size;
  const float* x0   = (const float*)d_in[0];
  const float* Wq   = (const float*)d_in[1];
  const float* bq   = (const float*)d_in[2];
  const float* Wk   = (const float*)d_in[3];
  const float* bk   = (const float*)d_in[4];
  const float* Wv   = (const float*)d_in[5];
  const float* bv   = (const float*)d_in[6];
  const float* Wo   = (const float*)d_in[7];
  const float* bo   = (const float*)d_in[8];
  const float* ln1w = (const float*)d_in[9];
  const float* ln1b = (const float*)d_in[10];
  const float* W1   = (const float*)d_in[11];
  const float* b1   = (const float*)d_in[12];
  const float* W2   = (const float*)d_in[13];
  const float* b2   = (const float*)d_in[14];
  const float* ln2w = (const float*)d_in[15];
  const float* ln2b = (const float*)d_in[16];
  const float* lnfw = (const float*)d_in[17];
  const float* lnfb = (const float*)d_in[18];

  char* ws = (char*)d_ws;
  size_t off = 0;
  auto alloc = [&](size_t bytes) {
    char* p = ws + off; off += (bytes + 255) & ~(size_t)255; return p;
  };
  u16*   wqkv_t = (u16*)alloc((size_t)L_N * QKV_N * D_N * 2);  // (L, 2304, 768)
  u16*   wo_t   = (u16*)alloc((size_t)L_N * D_N * D_N * 2);
  u16*   w1_t   = (u16*)alloc((size_t)L_N * D_N * F_N * 2);    // (L, 3072, 768)
  u16*   w2_t   = (u16*)alloc((size_t)L_N * D_N * F_N * 2);    // (L, 768, 3072)
  float* bqkv   = (float*)alloc((size_t)L_N * QKV_N * 4);
  u16*   x_b    = (u16*)alloc((size_t)BS_N * D_N * 2);         // bf16 residual stream
  u16*   xn_b   = (u16*)alloc((size_t)BS_N * D_N * 2);
  u16*   qkvb   = (u16*)alloc((size_t)BS_N * QKV_N * 2);
  u16*   ab     = (u16*)alloc((size_t)BS_N * D_N * 2);
  u16*   hb     = (u16*)alloc((size_t)BS_N * F_N * 2);         // 25.2 MB; aliased by Opart
  float* ml     = (float*)alloc((size_t)2 * B_N * H_N * S_N * 2 * 4);
  u32*   flags  = (u32*)alloc((size_t)L_N * NFLG * 4);
  float* opart  = (float*)hb;   // 2*B*H*S*64 fp32 = 25.2 MB, dead during attention

  zero_flags_kernel<<<(L_N * NFLG + 255) / 256, 256, 0, stream>>>(flags, L_N * NFLG);

  const size_t dd = (size_t)D_N * D_N, qs = (size_t)QKV_N * D_N, df = (size_t)D_N * F_N;
  transpose_cast_kernel<<<dim3(D_N/32, D_N/32, L_N), 256, 0, stream>>>(Wq, wqkv_t, D_N, D_N, qs, 0);
  transpose_cast_kernel<<<dim3(D_N/32, D_N/32, L_N), 256, 0, stream>>>(Wk, wqkv_t, D_N, D_N, qs, 768);
  transpose_cast_kernel<<<dim3(D_N/32, D_N/32, L_N), 256, 0, stream>>>(Wv, wqkv_t, D_N, D_N, qs, 1536);
  transpose_cast_kernel<<<dim3(D_N/32, D_N/32, L_N), 256, 0, stream>>>(Wo, wo_t, D_N, D_N, dd, 0);
  transpose_cast_kernel<<<dim3(F_N/32, D_N/32, L_N), 256, 0, stream>>>(W1, w1_t, D_N, F_N, df, 0);
  transpose_cast_kernel<<<dim3(D_N/32, F_N/32, L_N), 256, 0, stream>>>(W2, w2_t, F_N, D_N, df, 0);
  concat_bias_kernel<<<(L_N * QKV_N) / 256, 256, 0, stream>>>(bq, bk, bv, bqkv);

  const dim3 gQKV(BS_N / 128, QKV_N / 128);  // (32, 18)
  const dim3 gF  (BS_N / 128, F_N / 128);    // (32, 24)
  const dim3 g64 (BS_N / 64,  D_N / 64);     // (64, 12) for Wo / W2
  const dim3 gA  (NQT, B_N * H_N, 2);        // (16, 24, 2) -> 768 blocks, 3/CU

  for (int i = 0; i < L_N; ++i) {
    if (i == 0)
      ln_kernel<false><<<BS_N, 256, 0, stream>>>(x0, ln1w, ln1b, nullptr, xn_b);
    else
      ln_kernel<true><<<BS_N, 256, 0, stream>>>(x_b, ln1w + i * D_N, ln1b + i * D_N, nullptr, xn_b);
    gemm_kernel<false,true,true><<<gQKV, 256, 0, stream>>>(
        xn_b, wqkv_t + (size_t)i * qs, bqkv + (size_t)i * QKV_N, qkvb, BS_N, QKV_N, D_N);
    attn_kernel<<<gA, 256, 0, stream>>>(qkvb, opart, ml, ab, flags + (size_t)i * NFLG);
    gemm64_kernel<<<g64, 256, 0, stream>>>(
        ab, wo_t + (size_t)i * dd, bo + i * D_N, xn_b, x_b, BS_N, D_N, D_N);
    ln_kernel<true><<<BS_N, 256, 0, stream>>>(x_b, ln2w + i * D_N, ln2b + i * D_N, nullptr, xn_b);
    gemm_kernel<true,true,false><<<gF, 256, 0, stream>>>(
        xn_b, w1_t + (size_t)i * df, b1 + i * F_N, hb, BS_N, F_N, D_N);
    gemm64_kernel<<<g64, 256, 0, stream>>>(
        hb, w2_t + (size_t)i * df, b2 + i * D_N, xn_b, x_b, BS_N, D_N, F_N);
  }
  ln_kernel<true><<<BS_N, 256, 0, stream>>>(x_b, lnfw, lnfb, (float*)d_out, nullptr);
}

// Round 14
// 1392.064 us; speedup vs baseline: 1.1977x; 1.1977x over previous
//
#include <hip/hip_runtime.h>
#include <stdint.h>

typedef unsigned short u16;
typedef unsigned int   u32;

#define L_N  6
#define D_N  768
#define F_N  3072
#define H_N  12
#define B_N  2
#define S_N  2048
#define BS_N 4096   // B*S rows
#define QKV_N 2304  // fused q|k|v width
#define CSC  0.18033688011112042f   // 1/sqrt(64) * log2(e), folded into Q
#define DTHR 11.54f                 // 8 * log2(e): defer-max threshold (exp2 domain)

using bf16x8 = __attribute__((ext_vector_type(8))) short;
using f32x4  = __attribute__((ext_vector_type(4))) float;
using f32x16 = __attribute__((ext_vector_type(16))) float;
using u32x2  = __attribute__((ext_vector_type(2))) unsigned int;

__device__ __forceinline__ u16 f2bf(float f) {
  u32 x = __builtin_bit_cast(u32, f);
  x += 0x7FFFu + ((x >> 16) & 1u);
  return (u16)(x >> 16);
}

__device__ __forceinline__ float bf2f(u16 v) {
  return __builtin_bit_cast(float, (u32)v << 16);
}

__device__ __forceinline__ u32 cvt_pk_bf16(float lo, float hi) {
  u32 r;
  asm("v_cvt_pk_bf16_f32 %0, %1, %2" : "=v"(r) : "v"(lo), "v"(hi));
  return r;
}

#define GLOAD16(g, l)                                                                     \
  __builtin_amdgcn_global_load_lds((const __attribute__((address_space(1))) void*)(g),    \
                                   (__attribute__((address_space(3))) void*)(l), 16, 0, 0)

// ---------- transpose + cast: in (L,K,N) f32 -> out rows at (l*lstride + (rowoff+n)*K) bf16 ----------
__global__ __launch_bounds__(256) void transpose_cast_kernel(
    const float* __restrict__ in, u16* __restrict__ out, int K, int N,
    size_t out_lstride, int out_rowoff)
{
  __shared__ float tile[32][33];
  const int l  = blockIdx.z;
  const int n0 = blockIdx.x * 32, k0 = blockIdx.y * 32;
  const int tx = threadIdx.x & 31, ty = threadIdx.x >> 5;
  const float* src = in + (size_t)l * K * N;
  u16* dst = out + (size_t)l * out_lstride + (size_t)out_rowoff * K;
#pragma unroll
  for (int i = 0; i < 4; ++i)
    tile[ty + i * 8][tx] = src[(size_t)(k0 + ty + i * 8) * N + n0 + tx];
  __syncthreads();
#pragma unroll
  for (int i = 0; i < 4; ++i)
    dst[(size_t)(n0 + ty + i * 8) * K + k0 + tx] = f2bf(tile[tx][ty + i * 8]);
}

// ---------- concat q|k|v biases into (L, 2304) ----------
__global__ __launch_bounds__(256) void concat_bias_kernel(
    const float* __restrict__ bq, const float* __restrict__ bk,
    const float* __restrict__ bv, float* __restrict__ out)
{
  const int i = blockIdx.x * 256 + threadIdx.x;   // exact grid: L*2304
  const int l = i / QKV_N, c = i - l * QKV_N;
  float v = (c < 768) ? bq[l * 768 + c]
          : (c < 1536) ? bk[l * 768 + c - 768]
                       : bv[l * 768 + c - 1536];
  out[i] = v;
}

// ---------- LayerNorm: one row (768) per block; input fp32 or bf16 ----------
template<bool BF16IN>
__global__ __launch_bounds__(256) void ln_kernel(
    const void* __restrict__ xv, const float* __restrict__ w, const float* __restrict__ b,
    float* __restrict__ outF, u16* __restrict__ outB)
{
  const int row = blockIdx.x, tid = threadIdx.x;
  float v[3];
  float s = 0.f;
  if (BF16IN) {
    const u16* xr = (const u16*)xv + (size_t)row * D_N;
#pragma unroll
    for (int i = 0; i < 3; ++i) { v[i] = bf2f(xr[tid + i * 256]); s += v[i]; }
  } else {
    const float* xr = (const float*)xv + (size_t)row * D_N;
#pragma unroll
    for (int i = 0; i < 3; ++i) { v[i] = xr[tid + i * 256]; s += v[i]; }
  }
  __shared__ float red[8];
  const int wave = tid >> 6, lane = tid & 63;
#pragma unroll
  for (int o = 32; o > 0; o >>= 1) s += __shfl_down(s, o, 64);
  if (lane == 0) red[wave] = s;
  __syncthreads();
  const float mu = (red[0] + red[1] + red[2] + red[3]) * (1.f / D_N);
  float d2 = 0.f;
#pragma unroll
  for (int i = 0; i < 3; ++i) { float d = v[i] - mu; d2 += d * d; }
#pragma unroll
  for (int o = 32; o > 0; o >>= 1) d2 += __shfl_down(d2, o, 64);
  if (lane == 0) red[4 + wave] = d2;
  __syncthreads();
  const float var = (red[4] + red[5] + red[6] + red[7]) * (1.f / D_N);
  const float rs = rsqrtf(var + 1e-5f);
#pragma unroll
  for (int i = 0; i < 3; ++i) {
    const int c = tid + i * 256;
    const float o = (v[i] - mu) * rs * w[c] + b[c];
    if (outF) outF[(size_t)row * D_N + c] = o;
    if (outB) outB[(size_t)row * D_N + c] = f2bf(o);
  }
}

// ---------- GEMM 128x128: C = A @ Wt^T + bias, fused epilogue (W1) ----------
template<bool GELU, bool OUTB, bool SCALEQ>
__global__ __launch_bounds__(256) void gemm_kernel(
    const u16* __restrict__ A, const u16* __restrict__ Wt,
    const float* __restrict__ bias,
    u16* __restrict__ outB, int M, int N, int K)
{
  __shared__ __align__(16) u16 As[2][128 * 32];
  __shared__ __align__(16) u16 Bs[2][128 * 32];
  const int tid  = threadIdx.x;
  const int wave = tid >> 6, lane = tid & 63;
  const int lr = lane & 15, lg = lane >> 4;
  const int row0 = blockIdx.x * 128, col0 = blockIdx.y * 128;
  const int wr = (wave >> 1) * 64, wc = (wave & 1) * 64;

  const int cb0 = wave * 64;
  const int cb1 = 256 + wave * 64;
  const int r0s = (cb0 + lane) >> 2, c0s = ((cb0 + lane) & 3) << 3;
  const int r1s = (cb1 + lane) >> 2, c1s = ((cb1 + lane) & 3) << 3;

  f32x4 acc[4][4] = {};

#define STAGE(cbuf, kk)                                                           \
  do {                                                                            \
    GLOAD16(A  + (size_t)(row0 + r0s) * K + (kk) + c0s, &As[cbuf][cb0 * 8]);      \
    GLOAD16(Wt + (size_t)(col0 + r0s) * K + (kk) + c0s, &Bs[cbuf][cb0 * 8]);      \
    GLOAD16(A  + (size_t)(row0 + r1s) * K + (kk) + c1s, &As[cbuf][cb1 * 8]);      \
    GLOAD16(Wt + (size_t)(col0 + r1s) * K + (kk) + c1s, &Bs[cbuf][cb1 * 8]);      \
  } while (0)

  STAGE(0, 0);
  __syncthreads();

  int c = 0;
  for (int k0 = 0; k0 < K; k0 += 32, c ^= 1) {
    if (k0 + 32 < K) STAGE(c ^ 1, k0 + 32);
    bf16x8 af[4], bfr[4];
#pragma unroll
    for (int m = 0; m < 4; ++m)
      af[m] = *(const bf16x8*)&As[c][(wr + m * 16 + lr) * 32 + lg * 8];
#pragma unroll
    for (int n = 0; n < 4; ++n)
      bfr[n] = *(const bf16x8*)&Bs[c][(wc + n * 16 + lr) * 32 + lg * 8];
    __builtin_amdgcn_s_setprio(1);
#pragma unroll
    for (int m = 0; m < 4; ++m)
#pragma unroll
      for (int n = 0; n < 4; ++n)
        acc[m][n] = __builtin_amdgcn_mfma_f32_16x16x32_bf16(af[m], bfr[n], acc[m][n], 0, 0, 0);
    __builtin_amdgcn_s_setprio(0);
    __syncthreads();
  }
#undef STAGE

#pragma unroll
  for (int m = 0; m < 4; ++m)
#pragma unroll
    for (int n = 0; n < 4; ++n) {
      const int col = col0 + wc + n * 16 + lr;
      const float bv = bias[col];
#pragma unroll
      for (int r = 0; r < 4; ++r) {
        const int row = row0 + wr + m * 16 + lg * 4 + r;
        float v = acc[m][n][r] + bv;
        if (GELU) v = 0.5f * v * (1.f + erff(v * 0.70710678118f));
        if (SCALEQ && col < 768) v *= CSC;
        const size_t idx = (size_t)row * N + col;
        if (OUTB) outB[idx] = f2bf(v);
      }
    }
}

// ---------- GEMM 64x64: templated epilogue ----------
// RES: +bf16 residual. SCALEQ: scale q-columns (col<768) by CSC (QKV).
template<bool RES, bool SCALEQ>
__global__ __launch_bounds__(256) void gemm64_kernel(
    const u16* __restrict__ A, const u16* __restrict__ Wt,
    const float* __restrict__ bias, const u16* __restrict__ resid,
    u16* __restrict__ outB, int M, int N, int K)
{
  __shared__ __align__(16) u16 As[2][64 * 32];
  __shared__ __align__(16) u16 Bs[2][64 * 32];
  const int tid  = threadIdx.x;
  const int wave = tid >> 6, lane = tid & 63;
  const int lr = lane & 15, lg = lane >> 4;
  const int row0 = blockIdx.x * 64, col0 = blockIdx.y * 64;
  const int wr = (wave >> 1) * 32, wc = (wave & 1) * 32;

  const int cb = wave * 64;
  const int ch = cb + lane;
  const int rs = ch >> 2, cs = (ch & 3) << 3;

  f32x4 acc[2][2] = {};

#define STAGE64(cbuf, kk)                                                         \
  do {                                                                            \
    GLOAD16(A  + (size_t)(row0 + rs) * K + (kk) + cs, &As[cbuf][cb * 8]);         \
    GLOAD16(Wt + (size_t)(col0 + rs) * K + (kk) + cs, &Bs[cbuf][cb * 8]);         \
  } while (0)

  STAGE64(0, 0);
  __syncthreads();

  int c = 0;
  for (int k0 = 0; k0 < K; k0 += 32, c ^= 1) {
    if (k0 + 32 < K) STAGE64(c ^ 1, k0 + 32);
    bf16x8 af[2], bfr[2];
#pragma unroll
    for (int m = 0; m < 2; ++m)
      af[m] = *(const bf16x8*)&As[c][(wr + m * 16 + lr) * 32 + lg * 8];
#pragma unroll
    for (int n = 0; n < 2; ++n)
      bfr[n] = *(const bf16x8*)&Bs[c][(wc + n * 16 + lr) * 32 + lg * 8];
    __builtin_amdgcn_s_setprio(1);
#pragma unroll
    for (int m = 0; m < 2; ++m)
#pragma unroll
      for (int n = 0; n < 2; ++n)
        acc[m][n] = __builtin_amdgcn_mfma_f32_16x16x32_bf16(af[m], bfr[n], acc[m][n], 0, 0, 0);
    __builtin_amdgcn_s_setprio(0);
    __syncthreads();
  }
#undef STAGE64

#pragma unroll
  for (int m = 0; m < 2; ++m)
#pragma unroll
    for (int n = 0; n < 2; ++n) {
      const int col = col0 + wc + n * 16 + lr;
      const float bv = bias[col];
#pragma unroll
      for (int r = 0; r < 4; ++r) {
        const int row = row0 + wr + m * 16 + lg * 4 + r;
        const size_t idx = (size_t)row * N + col;
        float v = acc[m][n][r] + bv;
        if (SCALEQ && col < 768) v *= CSC;
        if (RES) v += bf2f(resid[idx]);
        outB[idx] = f2bf(v);
      }
    }
}

// ---------- Flash attention v12 (round-12 best): v9 + split-KV x2 ----------
__global__ __launch_bounds__(256) void attn_kernel(
    const u16* __restrict__ QKV, float* __restrict__ Opart, float* __restrict__ Ml)
{
  constexpr int LDQ = QKV_N;
  constexpr int NT  = S_N / 64;   // 32
  __shared__ __align__(16) u16 Ks [64 * 72];   // [key][dh]
  __shared__ __align__(16) u16 VTs[64 * 72];   // [dh][key]
  const int tid  = threadIdx.x;
  const int wave = tid >> 6, lane = tid & 63;
  const int l31 = lane & 31, l5 = lane >> 5;
  const int bh = blockIdx.y;
  const int b = bh / H_N, h = bh - b * H_N;
  const int q0 = blockIdx.x * 128;
  const int z  = blockIdx.z;
  const int t0 = z * (NT / 2), t1 = (z + 1) * (NT / 2);
  const size_t rowbase = (size_t)b * S_N * LDQ;
  const u16* Qg = QKV + rowbase + h * 64;
  const u16* Kg = QKV + rowbase + 768 + h * 64;
  const u16* Vg = QKV + rowbase + 1536 + h * 64;

  const int qrow = q0 + wave * 32 + l31;
  bf16x8 qf[4];
#pragma unroll
  for (int ks = 0; ks < 4; ++ks)
    qf[ks] = *(const bf16x8*)(Qg + (size_t)qrow * LDQ + ks * 16 + l5 * 8);

  f32x16 o0 = {}, o1 = {};
  float m = -1e30f, l = 0.f;

  const int kr = tid >> 2, kc = (tid & 3) * 16;   // K staging coords
  const int pp = tid >> 3, cg = tid & 7;          // V staging coords

  const u16* gk0 = Kg + (size_t)(t0 * 64 + kr) * LDQ + kc;
  const u16* gv0 = Vg + (size_t)(t0 * 64 + 2 * pp) * LDQ + cg * 8;
  uint4 nk0 = *(const uint4*)gk0, nk1 = *(const uint4*)(gk0 + 8);
  uint4 nv0 = *(const uint4*)gv0, nv1 = *(const uint4*)(gv0 + LDQ);

  for (int t = t0; t < t1; ++t) {
    __syncthreads();
    { // LDS writes of tile t (K row-major; V transposed, jj-rotated u32 pairs)
      *(uint4*)&Ks[kr * 72 + kc]     = nk0;
      *(uint4*)&Ks[kr * 72 + kc + 8] = nk1;
      const u16* a0 = (const u16*)&nv0;
      const u16* a1 = (const u16*)&nv1;
#pragma unroll
      for (int j = 0; j < 8; ++j) {
        const int jj = (j + cg) & 7;
        *(u32*)&VTs[(cg * 8 + jj) * 72 + 2 * pp] = (u32)a0[jj] | ((u32)a1[jj] << 16);
      }
    }
    __syncthreads();

    if (t + 1 < t1) {
      const u16* gk1 = Kg + (size_t)((t + 1) * 64 + kr) * LDQ + kc;
      const u16* gv1 = Vg + (size_t)((t + 1) * 64 + 2 * pp) * LDQ + cg * 8;
      nk0 = *(const uint4*)gk1; nk1 = *(const uint4*)(gk1 + 8);
      nv0 = *(const uint4*)gv1; nv1 = *(const uint4*)(gv1 + LDQ);
    }

    // S^T = K @ Q^T: sv0/sv1 cover keys 0..31 / 32..63 x q=l31
    f32x16 sv0 = {}, sv1 = {};
    __builtin_amdgcn_s_setprio(1);
#pragma unroll
    for (int ks = 0; ks < 4; ++ks) {
      const bf16x8 kf0 = *(const bf16x8*)&Ks[(l31)      * 72 + ks * 16 + l5 * 8];
      const bf16x8 kf1 = *(const bf16x8*)&Ks[(32 + l31) * 72 + ks * 16 + l5 * 8];
      sv0 = __builtin_amdgcn_mfma_f32_32x32x16_bf16(kf0, qf[ks], sv0, 0, 0, 0);
      sv1 = __builtin_amdgcn_mfma_f32_32x32x16_bf16(kf1, qf[ks], sv1, 0, 0, 0);
    }
    __builtin_amdgcn_s_setprio(0);

    // online softmax (exp2 domain; scale pre-folded into Q)
    float mx = sv0[0];
#pragma unroll
    for (int i = 0; i < 16; ++i) mx = fmaxf(mx, sv0[i]);
#pragma unroll
    for (int i = 0; i < 16; ++i) mx = fmaxf(mx, sv1[i]);
    {
      const u32 mb = __builtin_bit_cast(u32, mx);
      const u32x2 rr = __builtin_amdgcn_permlane32_swap(mb, mb, false, false);
      mx = fmaxf(__builtin_bit_cast(float, rr[0]), __builtin_bit_cast(float, rr[1]));
    }
    if (!__all(mx - m <= DTHR)) {
      const float mn = fmaxf(m, mx);
      const float al = __builtin_amdgcn_exp2f(m - mn);
      m = mn;
      l *= al;
#pragma unroll
      for (int i = 0; i < 16; ++i) { o0[i] *= al; o1[i] *= al; }
    }
    float rs = 0.f;
#pragma unroll
    for (int i = 0; i < 16; ++i) {
      const float e = __builtin_amdgcn_exp2f(sv0[i] - m);
      sv0[i] = e; rs += e;
    }
#pragma unroll
    for (int i = 0; i < 16; ++i) {
      const float e = __builtin_amdgcn_exp2f(sv1[i] - m);
      sv1[i] = e; rs += e;
    }
    {
      const u32 sb = __builtin_bit_cast(u32, rs);
      const u32x2 rr = __builtin_amdgcn_permlane32_swap(sb, sb, false, false);
      rs = __builtin_bit_cast(float, rr[0]) + __builtin_bit_cast(float, rr[1]);
    }
    l += rs;

    // P -> bf16 B-fragments in-register (T12)
    bf16x8 pb[4];
#pragma unroll
    for (int kb = 0; kb < 2; ++kb) {
      const f32x16& p = kb ? sv1 : sv0;
#pragma unroll
      for (int half = 0; half < 2; ++half) {
        const int o8 = half * 8;
        const u32 a0 = cvt_pk_bf16(p[o8 + 0], p[o8 + 1]);
        const u32 b0 = cvt_pk_bf16(p[o8 + 4], p[o8 + 5]);
        const u32 a1 = cvt_pk_bf16(p[o8 + 2], p[o8 + 3]);
        const u32 b1 = cvt_pk_bf16(p[o8 + 6], p[o8 + 7]);
        const u32x2 r0 = __builtin_amdgcn_permlane32_swap(a0, b0, false, false);
        const u32x2 r1 = __builtin_amdgcn_permlane32_swap(a1, b1, false, false);
        u32 w[4] = { r0[0], r1[0], r0[1], r1[1] };
        pb[kb * 2 + half] = __builtin_bit_cast(bf16x8, *(const uint4*)w);
      }
    }

    // PV
    __builtin_amdgcn_s_setprio(1);
#pragma unroll
    for (int ks2 = 0; ks2 < 4; ++ks2) {
      const bf16x8 vf0 = *(const bf16x8*)&VTs[(l31)      * 72 + ks2 * 16 + l5 * 8];
      const bf16x8 vf1 = *(const bf16x8*)&VTs[(32 + l31) * 72 + ks2 * 16 + l5 * 8];
      o0 = __builtin_amdgcn_mfma_f32_32x32x16_bf16(vf0, pb[ks2], o0, 0, 0, 0);
      o1 = __builtin_amdgcn_mfma_f32_32x32x16_bf16(vf1, pb[ks2], o1, 0, 0, 0);
    }
    __builtin_amdgcn_s_setprio(0);
  }

  // partial epilogue: unnormalized fp32 O + (m, l) per q-row
  float* op = Opart + (((size_t)z * B_N * H_N + bh) * S_N + qrow) * 64;
#pragma unroll
  for (int r = 0; r < 16; r += 2) {
    const int dh = (r & 3) + 8 * (r >> 2) + 4 * l5;
    *(float2*)(op + dh)      = float2{o0[r], o0[r + 1]};
    *(float2*)(op + dh + 32) = float2{o1[r], o1[r + 1]};
  }
  if (l5 == 0) {
    float* mlp = Ml + (((size_t)z * B_N * H_N + bh) * S_N + qrow) * 2;
    mlp[0] = m; mlp[1] = l;
  }
}

// ---------- combine KV-half partials -> ab (bf16, head-interleaved) ----------
__global__ __launch_bounds__(256) void attn_combine_kernel(
    const float* __restrict__ Opart, const float* __restrict__ Ml, u16* __restrict__ O)
{
  constexpr size_t HALF = (size_t)B_N * H_N * S_N;   // rows per z-half
  const int tid = threadIdx.x;
  const int lane = tid & 63, grp = tid >> 6;
  const size_t row = (size_t)blockIdx.x * 4 + grp;   // (b*H + h)*S + s
  const float* p0 = Opart + row * 64;
  const float* p1 = p0 + HALF * 64;
  const float m0 = Ml[row * 2], l0 = Ml[row * 2 + 1];
  const float m1 = Ml[(row + HALF) * 2], l1 = Ml[(row + HALF) * 2 + 1];
  const float mm = fmaxf(m0, m1);
  const float a0 = __builtin_amdgcn_exp2f(m0 - mm);
  const float a1 = __builtin_amdgcn_exp2f(m1 - mm);
  const float inv = 1.f / (a0 * l0 + a1 * l1);
  const float o = (a0 * p0[lane] + a1 * p1[lane]) * inv;
  const int bh = (int)(row / S_N), s = (int)(row % S_N);
  const int b = bh / H_N, h = bh - b * H_N;
  O[((size_t)b * S_N + s) * D_N + h * 64 + lane] = f2bf(o);
}

// ---------- orchestration ----------
extern "C" void kernel_launch(void* const* d_in, const int* in_sizes, int n_in,
                              void* d_out, int out_size, void* d_ws, size_t ws_size,
                              hipStream_t stream)
{
  (void)in_sizes; (void)n_in; (void)out_size; (void)ws_size;
  const float* x0   = (const float*)d_in[0];
  const float* Wq   = (const float*)d_in[1];
  const float* bq   = (const float*)d_in[2];
  const float* Wk   = (const float*)d_in[3];
  const float* bk   = (const float*)d_in[4];
  const float* Wv   = (const float*)d_in[5];
  const float* bv   = (const float*)d_in[6];
  const float* Wo   = (const float*)d_in[7];
  const float* bo   = (const float*)d_in[8];
  const float* ln1w = (const float*)d_in[9];
  const float* ln1b = (const float*)d_in[10];
  const float* W1   = (const float*)d_in[11];
  const float* b1   = (const float*)d_in[12];
  const float* W2   = (const float*)d_in[13];
  const float* b2   = (const float*)d_in[14];
  const float* ln2w = (const float*)d_in[15];
  const float* ln2b = (const float*)d_in[16];
  const float* lnfw = (const float*)d_in[17];
  const float* lnfb = (const float*)d_in[18];

  char* ws = (char*)d_ws;
  size_t off = 0;
  auto alloc = [&](size_t bytes) {
    char* p = ws + off; off += (bytes + 255) & ~(size_t)255; return p;
  };
  u16*   wqkv_t = (u16*)alloc((size_t)L_N * QKV_N * D_N * 2);  // (L, 2304, 768)
  u16*   wo_t   = (u16*)alloc((size_t)L_N * D_N * D_N * 2);
  u16*   w1_t   = (u16*)alloc((size_t)L_N * D_N * F_N * 2);    // (L, 3072, 768)
  u16*   w2_t   = (u16*)alloc((size_t)L_N * D_N * F_N * 2);    // (L, 768, 3072)
  float* bqkv   = (float*)alloc((size_t)L_N * QKV_N * 4);
  u16*   x_b    = (u16*)alloc((size_t)BS_N * D_N * 2);         // bf16 residual stream
  u16*   xn_b   = (u16*)alloc((size_t)BS_N * D_N * 2);
  u16*   qkvb   = (u16*)alloc((size_t)BS_N * QKV_N * 2);
  u16*   ab     = (u16*)alloc((size_t)BS_N * D_N * 2);
  u16*   hb     = (u16*)alloc((size_t)BS_N * F_N * 2);         // 25.2 MB; aliased by Opart
  float* ml     = (float*)alloc((size_t)2 * B_N * H_N * S_N * 2 * 4);
  float* opart  = (float*)hb;   // 2*B*H*S*64 fp32 = 25.2 MB, dead during attention

  const size_t dd = (size_t)D_N * D_N, qs = (size_t)QKV_N * D_N, df = (size_t)D_N * F_N;
  transpose_cast_kernel<<<dim3(D_N/32, D_N/32, L_N), 256, 0, stream>>>(Wq, wqkv_t, D_N, D_N, qs, 0);
  transpose_cast_kernel<<<dim3(D_N/32, D_N/32, L_N), 256, 0, stream>>>(Wk, wqkv_t, D_N, D_N, qs, 768);
  transpose_cast_kernel<<<dim3(D_N/32, D_N/32, L_N), 256, 0, stream>>>(Wv, wqkv_t, D_N, D_N, qs, 1536);
  transpose_cast_kernel<<<dim3(D_N/32, D_N/32, L_N), 256, 0, stream>>>(Wo, wo_t, D_N, D_N, dd, 0);
  transpose_cast_kernel<<<dim3(F_N/32, D_N/32, L_N), 256, 0, stream>>>(W1, w1_t, D_N, F_N, df, 0);
  transpose_cast_kernel<<<dim3(D_N/32, F_N/32, L_N), 256, 0, stream>>>(W2, w2_t, F_N, D_N, df, 0);
  concat_bias_kernel<<<(L_N * QKV_N) / 256, 256, 0, stream>>>(bq, bk, bv, bqkv);

  const dim3 gQKV(BS_N / 64, QKV_N / 64);    // (64, 36) -> 2304 blocks, 9/CU balanced
  const dim3 gF  (BS_N / 128, F_N / 128);    // (32, 24) -> 768 blocks, 3/CU
  const dim3 g64 (BS_N / 64,  D_N / 64);     // (64, 12) -> 768 blocks, 3/CU
  const dim3 gA  (S_N / 128, B_N * H_N, 2);  // (16, 24, 2) -> 768 blocks, 3/CU

  for (int i = 0; i < L_N; ++i) {
    if (i == 0)
      ln_kernel<false><<<BS_N, 256, 0, stream>>>(x0, ln1w, ln1b, nullptr, xn_b);
    else
      ln_kernel<true><<<BS_N, 256, 0, stream>>>(x_b, ln1w + i * D_N, ln1b + i * D_N, nullptr, xn_b);
    gemm64_kernel<false,true><<<gQKV, 256, 0, stream>>>(
        xn_b, wqkv_t + (size_t)i * qs, bqkv + (size_t)i * QKV_N, nullptr, qkvb, BS_N, QKV_N, D_N);
    attn_kernel<<<gA, 256, 0, stream>>>(qkvb, opart, ml);
    attn_combine_kernel<<<(B_N * H_N * S_N) / 4, 256, 0, stream>>>(opart, ml, ab);
    gemm64_kernel<true,false><<<g64, 256, 0, stream>>>(
        ab, wo_t + (size_t)i * dd, bo + i * D_N, xn_b, x_b, BS_N, D_N, D_N);
    ln_kernel<true><<<BS_N, 256, 0, stream>>>(x_b, ln2w + i * D_N, ln2b + i * D_N, nullptr, xn_b);
    gemm_kernel<true,true,false><<<gF, 256, 0, stream>>>(
        xn_b, w1_t + (size_t)i * df, b1 + i * F_N, hb, BS_N, F_N, D_N);
    gemm64_kernel<true,false><<<g64, 256, 0, stream>>>(
        hb, w2_t + (size_t)i * df, b2 + i * D_N, xn_b, x_b, BS_N, D_N, F_N);
  }
  ln_kernel<true><<<BS_N, 256, 0, stream>>>(x_b, lnfw, lnfb, (float*)d_out, nullptr);
}

// Round 15
// 1333.071 us; speedup vs baseline: 1.2508x; 1.0443x over previous
//
#include <hip/hip_runtime.h>
#include <stdint.h>

typedef unsigned short u16;
typedef unsigned int   u32;

#define L_N  6
#define D_N  768
#define F_N  3072
#define H_N  12
#define B_N  2
#define S_N  2048
#define BS_N 4096   // B*S rows
#define QKV_N 2304  // fused q|k|v width
#define CSC  0.18033688011112042f   // 1/sqrt(64) * log2(e), folded into Q
#define DTHR 11.54f                 // 8 * log2(e): defer-max threshold (exp2 domain)

using bf16x8 = __attribute__((ext_vector_type(8))) short;
using f32x4  = __attribute__((ext_vector_type(4))) float;
using f32x16 = __attribute__((ext_vector_type(16))) float;
using u32x2  = __attribute__((ext_vector_type(2))) unsigned int;

__device__ __forceinline__ u16 f2bf(float f) {
  u32 x = __builtin_bit_cast(u32, f);
  x += 0x7FFFu + ((x >> 16) & 1u);
  return (u16)(x >> 16);
}

__device__ __forceinline__ float bf2f(u16 v) {
  return __builtin_bit_cast(float, (u32)v << 16);
}

__device__ __forceinline__ u32 cvt_pk_bf16(float lo, float hi) {
  u32 r;
  asm("v_cvt_pk_bf16_f32 %0, %1, %2" : "=v"(r) : "v"(lo), "v"(hi));
  return r;
}

#define GLOAD16(g, l)                                                                     \
  __builtin_amdgcn_global_load_lds((const __attribute__((address_space(1))) void*)(g),    \
                                   (__attribute__((address_space(3))) void*)(l), 16, 0, 0)

// ---------- transpose + cast: in (L,K,N) f32 -> out rows at (l*lstride + (rowoff+n)*K) bf16 ----------
__global__ __launch_bounds__(256) void transpose_cast_kernel(
    const float* __restrict__ in, u16* __restrict__ out, int K, int N,
    size_t out_lstride, int out_rowoff)
{
  __shared__ float tile[32][33];
  const int l  = blockIdx.z;
  const int n0 = blockIdx.x * 32, k0 = blockIdx.y * 32;
  const int tx = threadIdx.x & 31, ty = threadIdx.x >> 5;
  const float* src = in + (size_t)l * K * N;
  u16* dst = out + (size_t)l * out_lstride + (size_t)out_rowoff * K;
#pragma unroll
  for (int i = 0; i < 4; ++i)
    tile[ty + i * 8][tx] = src[(size_t)(k0 + ty + i * 8) * N + n0 + tx];
  __syncthreads();
#pragma unroll
  for (int i = 0; i < 4; ++i)
    dst[(size_t)(n0 + ty + i * 8) * K + k0 + tx] = f2bf(tile[tx][ty + i * 8]);
}

// ---------- concat q|k|v biases into (L, 2304) ----------
__global__ __launch_bounds__(256) void concat_bias_kernel(
    const float* __restrict__ bq, const float* __restrict__ bk,
    const float* __restrict__ bv, float* __restrict__ out)
{
  const int i = blockIdx.x * 256 + threadIdx.x;   // exact grid: L*2304
  const int l = i / QKV_N, c = i - l * QKV_N;
  float v = (c < 768) ? bq[l * 768 + c]
          : (c < 1536) ? bk[l * 768 + c - 768]
                       : bv[l * 768 + c - 1536];
  out[i] = v;
}

// ---------- LayerNorm: one row (768) per block; input fp32 or bf16 ----------
template<bool BF16IN>
__global__ __launch_bounds__(256) void ln_kernel(
    const void* __restrict__ xv, const float* __restrict__ w, const float* __restrict__ b,
    float* __restrict__ outF, u16* __restrict__ outB)
{
  const int row = blockIdx.x, tid = threadIdx.x;
  float v[3];
  float s = 0.f;
  if (BF16IN) {
    const u16* xr = (const u16*)xv + (size_t)row * D_N;
#pragma unroll
    for (int i = 0; i < 3; ++i) { v[i] = bf2f(xr[tid + i * 256]); s += v[i]; }
  } else {
    const float* xr = (const float*)xv + (size_t)row * D_N;
#pragma unroll
    for (int i = 0; i < 3; ++i) { v[i] = xr[tid + i * 256]; s += v[i]; }
  }
  __shared__ float red[8];
  const int wave = tid >> 6, lane = tid & 63;
#pragma unroll
  for (int o = 32; o > 0; o >>= 1) s += __shfl_down(s, o, 64);
  if (lane == 0) red[wave] = s;
  __syncthreads();
  const float mu = (red[0] + red[1] + red[2] + red[3]) * (1.f / D_N);
  float d2 = 0.f;
#pragma unroll
  for (int i = 0; i < 3; ++i) { float d = v[i] - mu; d2 += d * d; }
#pragma unroll
  for (int o = 32; o > 0; o >>= 1) d2 += __shfl_down(d2, o, 64);
  if (lane == 0) red[4 + wave] = d2;
  __syncthreads();
  const float var = (red[4] + red[5] + red[6] + red[7]) * (1.f / D_N);
  const float rs = rsqrtf(var + 1e-5f);
#pragma unroll
  for (int i = 0; i < 3; ++i) {
    const int c = tid + i * 256;
    const float o = (v[i] - mu) * rs * w[c] + b[c];
    if (outF) outF[(size_t)row * D_N + c] = o;
    if (outB) outB[(size_t)row * D_N + c] = f2bf(o);
  }
}

// ---------- GEMM 128x128: C = A @ Wt^T + bias, fused epilogue (W1) ----------
template<bool GELU, bool OUTB, bool SCALEQ>
__global__ __launch_bounds__(256) void gemm_kernel(
    const u16* __restrict__ A, const u16* __restrict__ Wt,
    const float* __restrict__ bias,
    u16* __restrict__ outB, int M, int N, int K)
{
  __shared__ __align__(16) u16 As[2][128 * 32];
  __shared__ __align__(16) u16 Bs[2][128 * 32];
  const int tid  = threadIdx.x;
  const int wave = tid >> 6, lane = tid & 63;
  const int lr = lane & 15, lg = lane >> 4;
  const int row0 = blockIdx.x * 128, col0 = blockIdx.y * 128;
  const int wr = (wave >> 1) * 64, wc = (wave & 1) * 64;

  const int cb0 = wave * 64;
  const int cb1 = 256 + wave * 64;
  const int r0s = (cb0 + lane) >> 2, c0s = ((cb0 + lane) & 3) << 3;
  const int r1s = (cb1 + lane) >> 2, c1s = ((cb1 + lane) & 3) << 3;

  f32x4 acc[4][4] = {};

#define STAGE(cbuf, kk)                                                           \
  do {                                                                            \
    GLOAD16(A  + (size_t)(row0 + r0s) * K + (kk) + c0s, &As[cbuf][cb0 * 8]);      \
    GLOAD16(Wt + (size_t)(col0 + r0s) * K + (kk) + c0s, &Bs[cbuf][cb0 * 8]);      \
    GLOAD16(A  + (size_t)(row0 + r1s) * K + (kk) + c1s, &As[cbuf][cb1 * 8]);      \
    GLOAD16(Wt + (size_t)(col0 + r1s) * K + (kk) + c1s, &Bs[cbuf][cb1 * 8]);      \
  } while (0)

  STAGE(0, 0);
  __syncthreads();

  int c = 0;
  for (int k0 = 0; k0 < K; k0 += 32, c ^= 1) {
    if (k0 + 32 < K) STAGE(c ^ 1, k0 + 32);
    bf16x8 af[4], bfr[4];
#pragma unroll
    for (int m = 0; m < 4; ++m)
      af[m] = *(const bf16x8*)&As[c][(wr + m * 16 + lr) * 32 + lg * 8];
#pragma unroll
    for (int n = 0; n < 4; ++n)
      bfr[n] = *(const bf16x8*)&Bs[c][(wc + n * 16 + lr) * 32 + lg * 8];
    __builtin_amdgcn_s_setprio(1);
#pragma unroll
    for (int m = 0; m < 4; ++m)
#pragma unroll
      for (int n = 0; n < 4; ++n)
        acc[m][n] = __builtin_amdgcn_mfma_f32_16x16x32_bf16(af[m], bfr[n], acc[m][n], 0, 0, 0);
    __builtin_amdgcn_s_setprio(0);
    __syncthreads();
  }
#undef STAGE

#pragma unroll
  for (int m = 0; m < 4; ++m)
#pragma unroll
    for (int n = 0; n < 4; ++n) {
      const int col = col0 + wc + n * 16 + lr;
      const float bv = bias[col];
#pragma unroll
      for (int r = 0; r < 4; ++r) {
        const int row = row0 + wr + m * 16 + lg * 4 + r;
        float v = acc[m][n][r] + bv;
        if (GELU) v = 0.5f * v * (1.f + erff(v * 0.70710678118f));
        if (SCALEQ && col < 768) v *= CSC;
        const size_t idx = (size_t)row * N + col;
        if (OUTB) outB[idx] = f2bf(v);
      }
    }
}

// ---------- GEMM 128x96 (QKV): 768 blocks = 3/CU balanced; +bias, SCALEQ, bf16 out ----------
__global__ __launch_bounds__(256) void gemm96_kernel(
    const u16* __restrict__ A, const u16* __restrict__ Wt,
    const float* __restrict__ bias, u16* __restrict__ outB,
    int M, int N, int K)
{
  __shared__ __align__(16) u16 As[2][128 * 32];   // 8 KB each
  __shared__ __align__(16) u16 Bs[2][96 * 32];    // 6 KB each
  const int tid  = threadIdx.x;
  const int wave = tid >> 6, lane = tid & 63;
  const int lr = lane & 15, lg = lane >> 4;
  const int row0 = blockIdx.x * 128, col0 = blockIdx.y * 96;
  const int wr = (wave >> 1) * 64, wc = (wave & 1) * 48;

  const int cb0 = wave * 64;            // chunks 0..255   (A it0 / B rows 0..63)
  const int cb1 = 256 + wave * 64;      // chunks 256..511 (A it1; B rows 64..95 for wave<2)
  const int r0s = (cb0 + lane) >> 2, c0s = ((cb0 + lane) & 3) << 3;
  const int r1s = (cb1 + lane) >> 2, c1s = ((cb1 + lane) & 3) << 3;

  f32x4 acc[4][3] = {};

#define STAGE96(cbuf, kk)                                                         \
  do {                                                                            \
    GLOAD16(A  + (size_t)(row0 + r0s) * K + (kk) + c0s, &As[cbuf][cb0 * 8]);      \
    GLOAD16(A  + (size_t)(row0 + r1s) * K + (kk) + c1s, &As[cbuf][cb1 * 8]);      \
    GLOAD16(Wt + (size_t)(col0 + r0s) * K + (kk) + c0s, &Bs[cbuf][cb0 * 8]);      \
    if (wave < 2)                                                                 \
      GLOAD16(Wt + (size_t)(col0 + r1s) * K + (kk) + c1s, &Bs[cbuf][cb1 * 8]);    \
  } while (0)

  STAGE96(0, 0);
  __syncthreads();

  int c = 0;
  for (int k0 = 0; k0 < K; k0 += 32, c ^= 1) {
    if (k0 + 32 < K) STAGE96(c ^ 1, k0 + 32);
    bf16x8 af[4], bfr[3];
#pragma unroll
    for (int m = 0; m < 4; ++m)
      af[m] = *(const bf16x8*)&As[c][(wr + m * 16 + lr) * 32 + lg * 8];
#pragma unroll
    for (int n = 0; n < 3; ++n)
      bfr[n] = *(const bf16x8*)&Bs[c][(wc + n * 16 + lr) * 32 + lg * 8];
    __builtin_amdgcn_s_setprio(1);
#pragma unroll
    for (int m = 0; m < 4; ++m)
#pragma unroll
      for (int n = 0; n < 3; ++n)
        acc[m][n] = __builtin_amdgcn_mfma_f32_16x16x32_bf16(af[m], bfr[n], acc[m][n], 0, 0, 0);
    __builtin_amdgcn_s_setprio(0);
    __syncthreads();
  }
#undef STAGE96

#pragma unroll
  for (int m = 0; m < 4; ++m)
#pragma unroll
    for (int n = 0; n < 3; ++n) {
      const int col = col0 + wc + n * 16 + lr;
      const float bv = bias[col];
#pragma unroll
      for (int r = 0; r < 4; ++r) {
        const int row = row0 + wr + m * 16 + lg * 4 + r;
        float v = acc[m][n][r] + bv;
        if (col < 768) v *= CSC;   // fold softmax scale into q
        outB[(size_t)row * N + col] = f2bf(v);
      }
    }
}

// ---------- GEMM 64x64 (Wo, W2): +bias +bf16resid -> bf16 out ----------
__global__ __launch_bounds__(256) void gemm64_kernel(
    const u16* __restrict__ A, const u16* __restrict__ Wt,
    const float* __restrict__ bias, const u16* __restrict__ resid,
    u16* __restrict__ outB, int M, int N, int K)
{
  __shared__ __align__(16) u16 As[2][64 * 32];
  __shared__ __align__(16) u16 Bs[2][64 * 32];
  const int tid  = threadIdx.x;
  const int wave = tid >> 6, lane = tid & 63;
  const int lr = lane & 15, lg = lane >> 4;
  const int row0 = blockIdx.x * 64, col0 = blockIdx.y * 64;
  const int wr = (wave >> 1) * 32, wc = (wave & 1) * 32;

  const int cb = wave * 64;
  const int ch = cb + lane;
  const int rs = ch >> 2, cs = (ch & 3) << 3;

  f32x4 acc[2][2] = {};

#define STAGE64(cbuf, kk)                                                         \
  do {                                                                            \
    GLOAD16(A  + (size_t)(row0 + rs) * K + (kk) + cs, &As[cbuf][cb * 8]);         \
    GLOAD16(Wt + (size_t)(col0 + rs) * K + (kk) + cs, &Bs[cbuf][cb * 8]);         \
  } while (0)

  STAGE64(0, 0);
  __syncthreads();

  int c = 0;
  for (int k0 = 0; k0 < K; k0 += 32, c ^= 1) {
    if (k0 + 32 < K) STAGE64(c ^ 1, k0 + 32);
    bf16x8 af[2], bfr[2];
#pragma unroll
    for (int m = 0; m < 2; ++m)
      af[m] = *(const bf16x8*)&As[c][(wr + m * 16 + lr) * 32 + lg * 8];
#pragma unroll
    for (int n = 0; n < 2; ++n)
      bfr[n] = *(const bf16x8*)&Bs[c][(wc + n * 16 + lr) * 32 + lg * 8];
    __builtin_amdgcn_s_setprio(1);
#pragma unroll
    for (int m = 0; m < 2; ++m)
#pragma unroll
      for (int n = 0; n < 2; ++n)
        acc[m][n] = __builtin_amdgcn_mfma_f32_16x16x32_bf16(af[m], bfr[n], acc[m][n], 0, 0, 0);
    __builtin_amdgcn_s_setprio(0);
    __syncthreads();
  }
#undef STAGE64

#pragma unroll
  for (int m = 0; m < 2; ++m)
#pragma unroll
    for (int n = 0; n < 2; ++n) {
      const int col = col0 + wc + n * 16 + lr;
      const float bv = bias[col];
#pragma unroll
      for (int r = 0; r < 4; ++r) {
        const int row = row0 + wr + m * 16 + lg * 4 + r;
        const size_t idx = (size_t)row * N + col;
        outB[idx] = f2bf(acc[m][n][r] + bv + bf2f(resid[idx]));
      }
    }
}

// ---------- Flash attention v12 (round-12 best): v9 + split-KV x2 ----------
__global__ __launch_bounds__(256) void attn_kernel(
    const u16* __restrict__ QKV, float* __restrict__ Opart, float* __restrict__ Ml)
{
  constexpr int LDQ = QKV_N;
  constexpr int NT  = S_N / 64;   // 32
  __shared__ __align__(16) u16 Ks [64 * 72];   // [key][dh]
  __shared__ __align__(16) u16 VTs[64 * 72];   // [dh][key]
  const int tid  = threadIdx.x;
  const int wave = tid >> 6, lane = tid & 63;
  const int l31 = lane & 31, l5 = lane >> 5;
  const int bh = blockIdx.y;
  const int b = bh / H_N, h = bh - b * H_N;
  const int q0 = blockIdx.x * 128;
  const int z  = blockIdx.z;
  const int t0 = z * (NT / 2), t1 = (z + 1) * (NT / 2);
  const size_t rowbase = (size_t)b * S_N * LDQ;
  const u16* Qg = QKV + rowbase + h * 64;
  const u16* Kg = QKV + rowbase + 768 + h * 64;
  const u16* Vg = QKV + rowbase + 1536 + h * 64;

  const int qrow = q0 + wave * 32 + l31;
  bf16x8 qf[4];
#pragma unroll
  for (int ks = 0; ks < 4; ++ks)
    qf[ks] = *(const bf16x8*)(Qg + (size_t)qrow * LDQ + ks * 16 + l5 * 8);

  f32x16 o0 = {}, o1 = {};
  float m = -1e30f, l = 0.f;

  const int kr = tid >> 2, kc = (tid & 3) * 16;   // K staging coords
  const int pp = tid >> 3, cg = tid & 7;          // V staging coords

  const u16* gk0 = Kg + (size_t)(t0 * 64 + kr) * LDQ + kc;
  const u16* gv0 = Vg + (size_t)(t0 * 64 + 2 * pp) * LDQ + cg * 8;
  uint4 nk0 = *(const uint4*)gk0, nk1 = *(const uint4*)(gk0 + 8);
  uint4 nv0 = *(const uint4*)gv0, nv1 = *(const uint4*)(gv0 + LDQ);

  for (int t = t0; t < t1; ++t) {
    __syncthreads();
    { // LDS writes of tile t (K row-major; V transposed, jj-rotated u32 pairs)
      *(uint4*)&Ks[kr * 72 + kc]     = nk0;
      *(uint4*)&Ks[kr * 72 + kc + 8] = nk1;
      const u16* a0 = (const u16*)&nv0;
      const u16* a1 = (const u16*)&nv1;
#pragma unroll
      for (int j = 0; j < 8; ++j) {
        const int jj = (j + cg) & 7;
        *(u32*)&VTs[(cg * 8 + jj) * 72 + 2 * pp] = (u32)a0[jj] | ((u32)a1[jj] << 16);
      }
    }
    __syncthreads();

    if (t + 1 < t1) {
      const u16* gk1 = Kg + (size_t)((t + 1) * 64 + kr) * LDQ + kc;
      const u16* gv1 = Vg + (size_t)((t + 1) * 64 + 2 * pp) * LDQ + cg * 8;
      nk0 = *(const uint4*)gk1; nk1 = *(const uint4*)(gk1 + 8);
      nv0 = *(const uint4*)gv1; nv1 = *(const uint4*)(gv1 + LDQ);
    }

    // S^T = K @ Q^T: sv0/sv1 cover keys 0..31 / 32..63 x q=l31
    f32x16 sv0 = {}, sv1 = {};
    __builtin_amdgcn_s_setprio(1);
#pragma unroll
    for (int ks = 0; ks < 4; ++ks) {
      const bf16x8 kf0 = *(const bf16x8*)&Ks[(l31)      * 72 + ks * 16 + l5 * 8];
      const bf16x8 kf1 = *(const bf16x8*)&Ks[(32 + l31) * 72 + ks * 16 + l5 * 8];
      sv0 = __builtin_amdgcn_mfma_f32_32x32x16_bf16(kf0, qf[ks], sv0, 0, 0, 0);
      sv1 = __builtin_amdgcn_mfma_f32_32x32x16_bf16(kf1, qf[ks], sv1, 0, 0, 0);
    }
    __builtin_amdgcn_s_setprio(0);

    // online softmax (exp2 domain; scale pre-folded into Q)
    float mx = sv0[0];
#pragma unroll
    for (int i = 0; i < 16; ++i) mx = fmaxf(mx, sv0[i]);
#pragma unroll
    for (int i = 0; i < 16; ++i) mx = fmaxf(mx, sv1[i]);
    {
      const u32 mb = __builtin_bit_cast(u32, mx);
      const u32x2 rr = __builtin_amdgcn_permlane32_swap(mb, mb, false, false);
      mx = fmaxf(__builtin_bit_cast(float, rr[0]), __builtin_bit_cast(float, rr[1]));
    }
    if (!__all(mx - m <= DTHR)) {
      const float mn = fmaxf(m, mx);
      const float al = __builtin_amdgcn_exp2f(m - mn);
      m = mn;
      l *= al;
#pragma unroll
      for (int i = 0; i < 16; ++i) { o0[i] *= al; o1[i] *= al; }
    }
    float rs = 0.f;
#pragma unroll
    for (int i = 0; i < 16; ++i) {
      const float e = __builtin_amdgcn_exp2f(sv0[i] - m);
      sv0[i] = e; rs += e;
    }
#pragma unroll
    for (int i = 0; i < 16; ++i) {
      const float e = __builtin_amdgcn_exp2f(sv1[i] - m);
      sv1[i] = e; rs += e;
    }
    {
      const u32 sb = __builtin_bit_cast(u32, rs);
      const u32x2 rr = __builtin_amdgcn_permlane32_swap(sb, sb, false, false);
      rs = __builtin_bit_cast(float, rr[0]) + __builtin_bit_cast(float, rr[1]);
    }
    l += rs;

    // P -> bf16 B-fragments in-register (T12)
    bf16x8 pb[4];
#pragma unroll
    for (int kb = 0; kb < 2; ++kb) {
      const f32x16& p = kb ? sv1 : sv0;
#pragma unroll
      for (int half = 0; half < 2; ++half) {
        const int o8 = half * 8;
        const u32 a0 = cvt_pk_bf16(p[o8 + 0], p[o8 + 1]);
        const u32 b0 = cvt_pk_bf16(p[o8 + 4], p[o8 + 5]);
        const u32 a1 = cvt_pk_bf16(p[o8 + 2], p[o8 + 3]);
        const u32 b1 = cvt_pk_bf16(p[o8 + 6], p[o8 + 7]);
        const u32x2 r0 = __builtin_amdgcn_permlane32_swap(a0, b0, false, false);
        const u32x2 r1 = __builtin_amdgcn_permlane32_swap(a1, b1, false, false);
        u32 w[4] = { r0[0], r1[0], r0[1], r1[1] };
        pb[kb * 2 + half] = __builtin_bit_cast(bf16x8, *(const uint4*)w);
      }
    }

    // PV
    __builtin_amdgcn_s_setprio(1);
#pragma unroll
    for (int ks2 = 0; ks2 < 4; ++ks2) {
      const bf16x8 vf0 = *(const bf16x8*)&VTs[(l31)      * 72 + ks2 * 16 + l5 * 8];
      const bf16x8 vf1 = *(const bf16x8*)&VTs[(32 + l31) * 72 + ks2 * 16 + l5 * 8];
      o0 = __builtin_amdgcn_mfma_f32_32x32x16_bf16(vf0, pb[ks2], o0, 0, 0, 0);
      o1 = __builtin_amdgcn_mfma_f32_32x32x16_bf16(vf1, pb[ks2], o1, 0, 0, 0);
    }
    __builtin_amdgcn_s_setprio(0);
  }

  // partial epilogue: unnormalized fp32 O + (m, l) per q-row
  float* op = Opart + (((size_t)z * B_N * H_N + bh) * S_N + qrow) * 64;
#pragma unroll
  for (int r = 0; r < 16; r += 2) {
    const int dh = (r & 3) + 8 * (r >> 2) + 4 * l5;
    *(float2*)(op + dh)      = float2{o0[r], o0[r + 1]};
    *(float2*)(op + dh + 32) = float2{o1[r], o1[r + 1]};
  }
  if (l5 == 0) {
    float* mlp = Ml + (((size_t)z * B_N * H_N + bh) * S_N + qrow) * 2;
    mlp[0] = m; mlp[1] = l;
  }
}

// ---------- combine KV-half partials -> ab (bf16, head-interleaved) ----------
__global__ __launch_bounds__(256) void attn_combine_kernel(
    const float* __restrict__ Opart, const float* __restrict__ Ml, u16* __restrict__ O)
{
  constexpr size_t HALF = (size_t)B_N * H_N * S_N;   // rows per z-half
  const int tid = threadIdx.x;
  const int lane = tid & 63, grp = tid >> 6;
  const size_t row = (size_t)blockIdx.x * 4 + grp;   // (b*H + h)*S + s
  const float* p0 = Opart + row * 64;
  const float* p1 = p0 + HALF * 64;
  const float m0 = Ml[row * 2], l0 = Ml[row * 2 + 1];
  const float m1 = Ml[(row + HALF) * 2], l1 = Ml[(row + HALF) * 2 + 1];
  const float mm = fmaxf(m0, m1);
  const float a0 = __builtin_amdgcn_exp2f(m0 - mm);
  const float a1 = __builtin_amdgcn_exp2f(m1 - mm);
  const float inv = 1.f / (a0 * l0 + a1 * l1);
  const float o = (a0 * p0[lane] + a1 * p1[lane]) * inv;
  const int bh = (int)(row / S_N), s = (int)(row % S_N);
  const int b = bh / H_N, h = bh - b * H_N;
  O[((size_t)b * S_N + s) * D_N + h * 64 + lane] = f2bf(o);
}

// ---------- orchestration ----------
extern "C" void kernel_launch(void* const* d_in, const int* in_sizes, int n_in,
                              void* d_out, int out_size, void* d_ws, size_t ws_size,
                              hipStream_t stream)
{
  (void)in_sizes; (void)n_in; (void)out_size; (void)ws_size;
  const float* x0   = (const float*)d_in[0];
  const float* Wq   = (const float*)d_in[1];
  const float* bq   = (const float*)d_in[2];
  const float* Wk   = (const float*)d_in[3];
  const float* bk   = (const float*)d_in[4];
  const float* Wv   = (const float*)d_in[5];
  const float* bv   = (const float*)d_in[6];
  const float* Wo   = (const float*)d_in[7];
  const float* bo   = (const float*)d_in[8];
  const float* ln1w = (const float*)d_in[9];
  const float* ln1b = (const float*)d_in[10];
  const float* W1   = (const float*)d_in[11];
  const float* b1   = (const float*)d_in[12];
  const float* W2   = (const float*)d_in[13];
  const float* b2   = (const float*)d_in[14];
  const float* ln2w = (const float*)d_in[15];
  const float* ln2b = (const float*)d_in[16];
  const float* lnfw = (const float*)d_in[17];
  const float* lnfb = (const float*)d_in[18];

  char* ws = (char*)d_ws;
  size_t off = 0;
  auto alloc = [&](size_t bytes) {
    char* p = ws + off; off += (bytes + 255) & ~(size_t)255; return p;
  };
  u16*   wqkv_t = (u16*)alloc((size_t)L_N * QKV_N * D_N * 2);  // (L, 2304, 768)
  u16*   wo_t   = (u16*)alloc((size_t)L_N * D_N * D_N * 2);
  u16*   w1_t   = (u16*)alloc((size_t)L_N * D_N * F_N * 2);    // (L, 3072, 768)
  u16*   w2_t   = (u16*)alloc((size_t)L_N * D_N * F_N * 2);    // (L, 768, 3072)
  float* bqkv   = (float*)alloc((size_t)L_N * QKV_N * 4);
  u16*   x_b    = (u16*)alloc((size_t)BS_N * D_N * 2);         // bf16 residual stream
  u16*   xn_b   = (u16*)alloc((size_t)BS_N * D_N * 2);
  u16*   qkvb   = (u16*)alloc((size_t)BS_N * QKV_N * 2);
  u16*   ab     = (u16*)alloc((size_t)BS_N * D_N * 2);
  u16*   hb     = (u16*)alloc((size_t)BS_N * F_N * 2);         // 25.2 MB; aliased by Opart
  float* ml     = (float*)alloc((size_t)2 * B_N * H_N * S_N * 2 * 4);
  float* opart  = (float*)hb;   // 2*B*H*S*64 fp32 = 25.2 MB, dead during attention

  const size_t dd = (size_t)D_N * D_N, qs = (size_t)QKV_N * D_N, df = (size_t)D_N * F_N;
  transpose_cast_kernel<<<dim3(D_N/32, D_N/32, L_N), 256, 0, stream>>>(Wq, wqkv_t, D_N, D_N, qs, 0);
  transpose_cast_kernel<<<dim3(D_N/32, D_N/32, L_N), 256, 0, stream>>>(Wk, wqkv_t, D_N, D_N, qs, 768);
  transpose_cast_kernel<<<dim3(D_N/32, D_N/32, L_N), 256, 0, stream>>>(Wv, wqkv_t, D_N, D_N, qs, 1536);
  transpose_cast_kernel<<<dim3(D_N/32, D_N/32, L_N), 256, 0, stream>>>(Wo, wo_t, D_N, D_N, dd, 0);
  transpose_cast_kernel<<<dim3(F_N/32, D_N/32, L_N), 256, 0, stream>>>(W1, w1_t, D_N, F_N, df, 0);
  transpose_cast_kernel<<<dim3(D_N/32, F_N/32, L_N), 256, 0, stream>>>(W2, w2_t, F_N, D_N, df, 0);
  concat_bias_kernel<<<(L_N * QKV_N) / 256, 256, 0, stream>>>(bq, bk, bv, bqkv);

  const dim3 gQKV(BS_N / 128, QKV_N / 96);   // (32, 24) -> 768 blocks, 3/CU balanced
  const dim3 gF  (BS_N / 128, F_N / 128);    // (32, 24) -> 768 blocks, 3/CU
  const dim3 g64 (BS_N / 64,  D_N / 64);     // (64, 12) -> 768 blocks, 3/CU
  const dim3 gA  (S_N / 128, B_N * H_N, 2);  // (16, 24, 2) -> 768 blocks, 3/CU

  for (int i = 0; i < L_N; ++i) {
    if (i == 0)
      ln_kernel<false><<<BS_N, 256, 0, stream>>>(x0, ln1w, ln1b, nullptr, xn_b);
    else
      ln_kernel<true><<<BS_N, 256, 0, stream>>>(x_b, ln1w + i * D_N, ln1b + i * D_N, nullptr, xn_b);
    gemm96_kernel<<<gQKV, 256, 0, stream>>>(
        xn_b, wqkv_t + (size_t)i * qs, bqkv + (size_t)i * QKV_N, qkvb, BS_N, QKV_N, D_N);
    attn_kernel<<<gA, 256, 0, stream>>>(qkvb, opart, ml);
    attn_combine_kernel<<<(B_N * H_N * S_N) / 4, 256, 0, stream>>>(opart, ml, ab);
    gemm64_kernel<<<g64, 256, 0, stream>>>(
        ab, wo_t + (size_t)i * dd, bo + i * D_N, xn_b, x_b, BS_N, D_N, D_N);
    ln_kernel<true><<<BS_N, 256, 0, stream>>>(x_b, ln2w + i * D_N, ln2b + i * D_N, nullptr, xn_b);
    gemm_kernel<true,true,false><<<gF, 256, 0, stream>>>(
        xn_b, w1_t + (size_t)i * df, b1 + i * F_N, hb, BS_N, F_N, D_N);
    gemm64_kernel<<<g64, 256, 0, stream>>>(
        hb, w2_t + (size_t)i * df, b2 + i * D_N, xn_b, x_b, BS_N, D_N, F_N);
  }
  ln_kernel<true><<<BS_N, 256, 0, stream>>>(x_b, lnfw, lnfb, (float*)d_out, nullptr);
}

// Round 16
// 1304.933 us; speedup vs baseline: 1.2777x; 1.0216x over previous
//
#include <hip/hip_runtime.h>
#include <stdint.h>

typedef unsigned short u16;
typedef unsigned int   u32;

#define L_N  6
#define D_N  768
#define F_N  3072
#define H_N  12
#define B_N  2
#define S_N  2048
#define BS_N 4096   // B*S rows
#define QKV_N 2304  // fused q|k|v width
#define CSC  0.18033688011112042f   // 1/sqrt(64) * log2(e), folded into Q
#define DTHR 11.54f                 // 8 * log2(e): defer-max threshold (exp2 domain)

using bf16x8 = __attribute__((ext_vector_type(8))) short;
using f32x4  = __attribute__((ext_vector_type(4))) float;
using f32x16 = __attribute__((ext_vector_type(16))) float;
using u32x2  = __attribute__((ext_vector_type(2))) unsigned int;

__device__ __forceinline__ u16 f2bf(float f) {
  u32 x = __builtin_bit_cast(u32, f);
  x += 0x7FFFu + ((x >> 16) & 1u);
  return (u16)(x >> 16);
}

__device__ __forceinline__ float bf2f(u16 v) {
  return __builtin_bit_cast(float, (u32)v << 16);
}

__device__ __forceinline__ u32 cvt_pk_bf16(float lo, float hi) {
  u32 r;
  asm("v_cvt_pk_bf16_f32 %0, %1, %2" : "=v"(r) : "v"(lo), "v"(hi));
  return r;
}

#define GLOAD16(g, l)                                                                     \
  __builtin_amdgcn_global_load_lds((const __attribute__((address_space(1))) void*)(g),    \
                                   (__attribute__((address_space(3))) void*)(l), 16, 0, 0)

// ---------- transpose + cast: in (L,K,N) f32 -> out rows at (l*lstride + (rowoff+n)*K) bf16 ----------
__global__ __launch_bounds__(256) void transpose_cast_kernel(
    const float* __restrict__ in, u16* __restrict__ out, int K, int N,
    size_t out_lstride, int out_rowoff)
{
  __shared__ float tile[32][33];
  const int l  = blockIdx.z;
  const int n0 = blockIdx.x * 32, k0 = blockIdx.y * 32;
  const int tx = threadIdx.x & 31, ty = threadIdx.x >> 5;
  const float* src = in + (size_t)l * K * N;
  u16* dst = out + (size_t)l * out_lstride + (size_t)out_rowoff * K;
#pragma unroll
  for (int i = 0; i < 4; ++i)
    tile[ty + i * 8][tx] = src[(size_t)(k0 + ty + i * 8) * N + n0 + tx];
  __syncthreads();
#pragma unroll
  for (int i = 0; i < 4; ++i)
    dst[(size_t)(n0 + ty + i * 8) * K + k0 + tx] = f2bf(tile[tx][ty + i * 8]);
}

// ---------- concat q|k|v biases into (L, 2304) ----------
__global__ __launch_bounds__(256) void concat_bias_kernel(
    const float* __restrict__ bq, const float* __restrict__ bk,
    const float* __restrict__ bv, float* __restrict__ out)
{
  const int i = blockIdx.x * 256 + threadIdx.x;   // exact grid: L*2304
  const int l = i / QKV_N, c = i - l * QKV_N;
  float v = (c < 768) ? bq[l * 768 + c]
          : (c < 1536) ? bk[l * 768 + c - 768]
                       : bv[l * 768 + c - 1536];
  out[i] = v;
}

// ---------- LayerNorm v2: wave-per-row, vectorized, zero-LDS ----------
// 4 waves/block = 4 rows; lane holds 12 elems (uint4 + uint2 bf16, or 3x float4).
template<bool BF16IN>
__global__ __launch_bounds__(256) void ln_kernel(
    const void* __restrict__ xv, const float* __restrict__ w, const float* __restrict__ b,
    float* __restrict__ outF, u16* __restrict__ outB)
{
  const int wave = threadIdx.x >> 6, lane = threadIdx.x & 63;
  const int row  = blockIdx.x * 4 + wave;
  const int c0 = lane * 8, c1 = 512 + lane * 4;   // bf16-path cols
  float v[12], wv[12], bv[12];

  if (BF16IN) {
    const u16* xr = (const u16*)xv + (size_t)row * D_N;
    const uint4 a  = *(const uint4*)(xr + c0);
    const uint2 a2 = *(const uint2*)(xr + c1);
    const u16* pa = (const u16*)&a;
#pragma unroll
    for (int i = 0; i < 8; ++i) v[i] = bf2f(pa[i]);
    const u16* pb = (const u16*)&a2;
#pragma unroll
    for (int i = 0; i < 4; ++i) v[8 + i] = bf2f(pb[i]);
    *(float4*)&wv[0] = *(const float4*)(w + c0);
    *(float4*)&wv[4] = *(const float4*)(w + c0 + 4);
    *(float4*)&wv[8] = *(const float4*)(w + c1);
    *(float4*)&bv[0] = *(const float4*)(b + c0);
    *(float4*)&bv[4] = *(const float4*)(b + c0 + 4);
    *(float4*)&bv[8] = *(const float4*)(b + c1);
  } else {
    const float* xr = (const float*)xv + (size_t)row * D_N;
#pragma unroll
    for (int r = 0; r < 3; ++r) {
      *(float4*)&v[r * 4]  = *(const float4*)(xr + r * 256 + lane * 4);
      *(float4*)&wv[r * 4] = *(const float4*)(w + r * 256 + lane * 4);
      *(float4*)&bv[r * 4] = *(const float4*)(b + r * 256 + lane * 4);
    }
  }

  float s = 0.f;
#pragma unroll
  for (int i = 0; i < 12; ++i) s += v[i];
#pragma unroll
  for (int o = 32; o > 0; o >>= 1) s += __shfl_xor(s, o, 64);
  const float mu = s * (1.f / D_N);
  float d2 = 0.f;
#pragma unroll
  for (int i = 0; i < 12; ++i) { const float d = v[i] - mu; d2 += d * d; }
#pragma unroll
  for (int o = 32; o > 0; o >>= 1) d2 += __shfl_xor(d2, o, 64);
  const float rs = rsqrtf(d2 * (1.f / D_N) + 1e-5f);

  float o[12];
#pragma unroll
  for (int i = 0; i < 12; ++i) o[i] = (v[i] - mu) * rs * wv[i] + bv[i];

  if (BF16IN) {
    if (outB) {
      u16* orow = outB + (size_t)row * D_N;
      u32 pk[4];
#pragma unroll
      for (int i = 0; i < 4; ++i) pk[i] = cvt_pk_bf16(o[2 * i], o[2 * i + 1]);
      *(uint4*)(orow + c0) = *(const uint4*)pk;
      u32 pk2[2] = { cvt_pk_bf16(o[8], o[9]), cvt_pk_bf16(o[10], o[11]) };
      *(uint2*)(orow + c1) = *(const uint2*)pk2;
    }
    if (outF) {
      float* frow = outF + (size_t)row * D_N;
      *(float4*)(frow + c0)     = *(const float4*)&o[0];
      *(float4*)(frow + c0 + 4) = *(const float4*)&o[4];
      *(float4*)(frow + c1)     = *(const float4*)&o[8];
    }
  } else {
    if (outB) {
      u16* orow = outB + (size_t)row * D_N;
#pragma unroll
      for (int r = 0; r < 3; ++r) {
        u32 pk2[2] = { cvt_pk_bf16(o[r * 4], o[r * 4 + 1]),
                       cvt_pk_bf16(o[r * 4 + 2], o[r * 4 + 3]) };
        *(uint2*)(orow + r * 256 + lane * 4) = *(const uint2*)pk2;
      }
    }
    if (outF) {
      float* frow = outF + (size_t)row * D_N;
#pragma unroll
      for (int r = 0; r < 3; ++r)
        *(float4*)(frow + r * 256 + lane * 4) = *(const float4*)&o[r * 4];
    }
  }
}

// ---------- GEMM 128x128: C = A @ Wt^T + bias, fused epilogue (W1) ----------
template<bool GELU, bool OUTB, bool SCALEQ>
__global__ __launch_bounds__(256) void gemm_kernel(
    const u16* __restrict__ A, const u16* __restrict__ Wt,
    const float* __restrict__ bias,
    u16* __restrict__ outB, int M, int N, int K)
{
  __shared__ __align__(16) u16 As[2][128 * 32];
  __shared__ __align__(16) u16 Bs[2][128 * 32];
  const int tid  = threadIdx.x;
  const int wave = tid >> 6, lane = tid & 63;
  const int lr = lane & 15, lg = lane >> 4;
  const int row0 = blockIdx.x * 128, col0 = blockIdx.y * 128;
  const int wr = (wave >> 1) * 64, wc = (wave & 1) * 64;

  const int cb0 = wave * 64;
  const int cb1 = 256 + wave * 64;
  const int r0s = (cb0 + lane) >> 2, c0s = ((cb0 + lane) & 3) << 3;
  const int r1s = (cb1 + lane) >> 2, c1s = ((cb1 + lane) & 3) << 3;

  f32x4 acc[4][4] = {};

#define STAGE(cbuf, kk)                                                           \
  do {                                                                            \
    GLOAD16(A  + (size_t)(row0 + r0s) * K + (kk) + c0s, &As[cbuf][cb0 * 8]);      \
    GLOAD16(Wt + (size_t)(col0 + r0s) * K + (kk) + c0s, &Bs[cbuf][cb0 * 8]);      \
    GLOAD16(A  + (size_t)(row0 + r1s) * K + (kk) + c1s, &As[cbuf][cb1 * 8]);      \
    GLOAD16(Wt + (size_t)(col0 + r1s) * K + (kk) + c1s, &Bs[cbuf][cb1 * 8]);      \
  } while (0)

  STAGE(0, 0);
  __syncthreads();

  int c = 0;
  for (int k0 = 0; k0 < K; k0 += 32, c ^= 1) {
    if (k0 + 32 < K) STAGE(c ^ 1, k0 + 32);
    bf16x8 af[4], bfr[4];
#pragma unroll
    for (int m = 0; m < 4; ++m)
      af[m] = *(const bf16x8*)&As[c][(wr + m * 16 + lr) * 32 + lg * 8];
#pragma unroll
    for (int n = 0; n < 4; ++n)
      bfr[n] = *(const bf16x8*)&Bs[c][(wc + n * 16 + lr) * 32 + lg * 8];
    __builtin_amdgcn_s_setprio(1);
#pragma unroll
    for (int m = 0; m < 4; ++m)
#pragma unroll
      for (int n = 0; n < 4; ++n)
        acc[m][n] = __builtin_amdgcn_mfma_f32_16x16x32_bf16(af[m], bfr[n], acc[m][n], 0, 0, 0);
    __builtin_amdgcn_s_setprio(0);
    __syncthreads();
  }
#undef STAGE

#pragma unroll
  for (int m = 0; m < 4; ++m)
#pragma unroll
    for (int n = 0; n < 4; ++n) {
      const int col = col0 + wc + n * 16 + lr;
      const float bv = bias[col];
#pragma unroll
      for (int r = 0; r < 4; ++r) {
        const int row = row0 + wr + m * 16 + lg * 4 + r;
        float v = acc[m][n][r] + bv;
        if (GELU) v = 0.5f * v * (1.f + erff(v * 0.70710678118f));
        if (SCALEQ && col < 768) v *= CSC;
        const size_t idx = (size_t)row * N + col;
        if (OUTB) outB[idx] = f2bf(v);
      }
    }
}

// ---------- GEMM 128x96 (QKV): 768 blocks = 3/CU balanced; +bias, SCALEQ, bf16 out ----------
__global__ __launch_bounds__(256) void gemm96_kernel(
    const u16* __restrict__ A, const u16* __restrict__ Wt,
    const float* __restrict__ bias, u16* __restrict__ outB,
    int M, int N, int K)
{
  __shared__ __align__(16) u16 As[2][128 * 32];   // 8 KB each
  __shared__ __align__(16) u16 Bs[2][96 * 32];    // 6 KB each
  const int tid  = threadIdx.x;
  const int wave = tid >> 6, lane = tid & 63;
  const int lr = lane & 15, lg = lane >> 4;
  const int row0 = blockIdx.x * 128, col0 = blockIdx.y * 96;
  const int wr = (wave >> 1) * 64, wc = (wave & 1) * 48;

  const int cb0 = wave * 64;            // chunks 0..255   (A it0 / B rows 0..63)
  const int cb1 = 256 + wave * 64;      // chunks 256..511 (A it1; B rows 64..95 for wave<2)
  const int r0s = (cb0 + lane) >> 2, c0s = ((cb0 + lane) & 3) << 3;
  const int r1s = (cb1 + lane) >> 2, c1s = ((cb1 + lane) & 3) << 3;

  f32x4 acc[4][3] = {};

#define STAGE96(cbuf, kk)                                                         \
  do {                                                                            \
    GLOAD16(A  + (size_t)(row0 + r0s) * K + (kk) + c0s, &As[cbuf][cb0 * 8]);      \
    GLOAD16(A  + (size_t)(row0 + r1s) * K + (kk) + c1s, &As[cbuf][cb1 * 8]);      \
    GLOAD16(Wt + (size_t)(col0 + r0s) * K + (kk) + c0s, &Bs[cbuf][cb0 * 8]);      \
    if (wave < 2)                                                                 \
      GLOAD16(Wt + (size_t)(col0 + r1s) * K + (kk) + c1s, &Bs[cbuf][cb1 * 8]);    \
  } while (0)

  STAGE96(0, 0);
  __syncthreads();

  int c = 0;
  for (int k0 = 0; k0 < K; k0 += 32, c ^= 1) {
    if (k0 + 32 < K) STAGE96(c ^ 1, k0 + 32);
    bf16x8 af[4], bfr[3];
#pragma unroll
    for (int m = 0; m < 4; ++m)
      af[m] = *(const bf16x8*)&As[c][(wr + m * 16 + lr) * 32 + lg * 8];
#pragma unroll
    for (int n = 0; n < 3; ++n)
      bfr[n] = *(const bf16x8*)&Bs[c][(wc + n * 16 + lr) * 32 + lg * 8];
    __builtin_amdgcn_s_setprio(1);
#pragma unroll
    for (int m = 0; m < 4; ++m)
#pragma unroll
      for (int n = 0; n < 3; ++n)
        acc[m][n] = __builtin_amdgcn_mfma_f32_16x16x32_bf16(af[m], bfr[n], acc[m][n], 0, 0, 0);
    __builtin_amdgcn_s_setprio(0);
    __syncthreads();
  }
#undef STAGE96

#pragma unroll
  for (int m = 0; m < 4; ++m)
#pragma unroll
    for (int n = 0; n < 3; ++n) {
      const int col = col0 + wc + n * 16 + lr;
      const float bv = bias[col];
#pragma unroll
      for (int r = 0; r < 4; ++r) {
        const int row = row0 + wr + m * 16 + lg * 4 + r;
        float v = acc[m][n][r] + bv;
        if (col < 768) v *= CSC;   // fold softmax scale into q
        outB[(size_t)row * N + col] = f2bf(v);
      }
    }
}

// ---------- GEMM 64x64 (Wo, W2): +bias +bf16resid -> bf16 out ----------
__global__ __launch_bounds__(256) void gemm64_kernel(
    const u16* __restrict__ A, const u16* __restrict__ Wt,
    const float* __restrict__ bias, const u16* __restrict__ resid,
    u16* __restrict__ outB, int M, int N, int K)
{
  __shared__ __align__(16) u16 As[2][64 * 32];
  __shared__ __align__(16) u16 Bs[2][64 * 32];
  const int tid  = threadIdx.x;
  const int wave = tid >> 6, lane = tid & 63;
  const int lr = lane & 15, lg = lane >> 4;
  const int row0 = blockIdx.x * 64, col0 = blockIdx.y * 64;
  const int wr = (wave >> 1) * 32, wc = (wave & 1) * 32;

  const int cb = wave * 64;
  const int ch = cb + lane;
  const int rs = ch >> 2, cs = (ch & 3) << 3;

  f32x4 acc[2][2] = {};

#define STAGE64(cbuf, kk)                                                         \
  do {                                                                            \
    GLOAD16(A  + (size_t)(row0 + rs) * K + (kk) + cs, &As[cbuf][cb * 8]);         \
    GLOAD16(Wt + (size_t)(col0 + rs) * K + (kk) + cs, &Bs[cbuf][cb * 8]);         \
  } while (0)

  STAGE64(0, 0);
  __syncthreads();

  int c = 0;
  for (int k0 = 0; k0 < K; k0 += 32, c ^= 1) {
    if (k0 + 32 < K) STAGE64(c ^ 1, k0 + 32);
    bf16x8 af[2], bfr[2];
#pragma unroll
    for (int m = 0; m < 2; ++m)
      af[m] = *(const bf16x8*)&As[c][(wr + m * 16 + lr) * 32 + lg * 8];
#pragma unroll
    for (int n = 0; n < 2; ++n)
      bfr[n] = *(const bf16x8*)&Bs[c][(wc + n * 16 + lr) * 32 + lg * 8];
    __builtin_amdgcn_s_setprio(1);
#pragma unroll
    for (int m = 0; m < 2; ++m)
#pragma unroll
      for (int n = 0; n < 2; ++n)
        acc[m][n] = __builtin_amdgcn_mfma_f32_16x16x32_bf16(af[m], bfr[n], acc[m][n], 0, 0, 0);
    __builtin_amdgcn_s_setprio(0);
    __syncthreads();
  }
#undef STAGE64

#pragma unroll
  for (int m = 0; m < 2; ++m)
#pragma unroll
    for (int n = 0; n < 2; ++n) {
      const int col = col0 + wc + n * 16 + lr;
      const float bv = bias[col];
#pragma unroll
      for (int r = 0; r < 4; ++r) {
        const int row = row0 + wr + m * 16 + lg * 4 + r;
        const size_t idx = (size_t)row * N + col;
        outB[idx] = f2bf(acc[m][n][r] + bv + bf2f(resid[idx]));
      }
    }
}

// ---------- Flash attention v12 (round-12 best): v9 + split-KV x2 ----------
__global__ __launch_bounds__(256) void attn_kernel(
    const u16* __restrict__ QKV, float* __restrict__ Opart, float* __restrict__ Ml)
{
  constexpr int LDQ = QKV_N;
  constexpr int NT  = S_N / 64;   // 32
  __shared__ __align__(16) u16 Ks [64 * 72];   // [key][dh]
  __shared__ __align__(16) u16 VTs[64 * 72];   // [dh][key]
  const int tid  = threadIdx.x;
  const int wave = tid >> 6, lane = tid & 63;
  const int l31 = lane & 31, l5 = lane >> 5;
  const int bh = blockIdx.y;
  const int b = bh / H_N, h = bh - b * H_N;
  const int q0 = blockIdx.x * 128;
  const int z  = blockIdx.z;
  const int t0 = z * (NT / 2), t1 = (z + 1) * (NT / 2);
  const size_t rowbase = (size_t)b * S_N * LDQ;
  const u16* Qg = QKV + rowbase + h * 64;
  const u16* Kg = QKV + rowbase + 768 + h * 64;
  const u16* Vg = QKV + rowbase + 1536 + h * 64;

  const int qrow = q0 + wave * 32 + l31;
  bf16x8 qf[4];
#pragma unroll
  for (int ks = 0; ks < 4; ++ks)
    qf[ks] = *(const bf16x8*)(Qg + (size_t)qrow * LDQ + ks * 16 + l5 * 8);

  f32x16 o0 = {}, o1 = {};
  float m = -1e30f, l = 0.f;

  const int kr = tid >> 2, kc = (tid & 3) * 16;   // K staging coords
  const int pp = tid >> 3, cg = tid & 7;          // V staging coords

  const u16* gk0 = Kg + (size_t)(t0 * 64 + kr) * LDQ + kc;
  const u16* gv0 = Vg + (size_t)(t0 * 64 + 2 * pp) * LDQ + cg * 8;
  uint4 nk0 = *(const uint4*)gk0, nk1 = *(const uint4*)(gk0 + 8);
  uint4 nv0 = *(const uint4*)gv0, nv1 = *(const uint4*)(gv0 + LDQ);

  for (int t = t0; t < t1; ++t) {
    __syncthreads();
    { // LDS writes of tile t (K row-major; V transposed, jj-rotated u32 pairs)
      *(uint4*)&Ks[kr * 72 + kc]     = nk0;
      *(uint4*)&Ks[kr * 72 + kc + 8] = nk1;
      const u16* a0 = (const u16*)&nv0;
      const u16* a1 = (const u16*)&nv1;
#pragma unroll
      for (int j = 0; j < 8; ++j) {
        const int jj = (j + cg) & 7;
        *(u32*)&VTs[(cg * 8 + jj) * 72 + 2 * pp] = (u32)a0[jj] | ((u32)a1[jj] << 16);
      }
    }
    __syncthreads();

    if (t + 1 < t1) {
      const u16* gk1 = Kg + (size_t)((t + 1) * 64 + kr) * LDQ + kc;
      const u16* gv1 = Vg + (size_t)((t + 1) * 64 + 2 * pp) * LDQ + cg * 8;
      nk0 = *(const uint4*)gk1; nk1 = *(const uint4*)(gk1 + 8);
      nv0 = *(const uint4*)gv1; nv1 = *(const uint4*)(gv1 + LDQ);
    }

    // S^T = K @ Q^T: sv0/sv1 cover keys 0..31 / 32..63 x q=l31
    f32x16 sv0 = {}, sv1 = {};
    __builtin_amdgcn_s_setprio(1);
#pragma unroll
    for (int ks = 0; ks < 4; ++ks) {
      const bf16x8 kf0 = *(const bf16x8*)&Ks[(l31)      * 72 + ks * 16 + l5 * 8];
      const bf16x8 kf1 = *(const bf16x8*)&Ks[(32 + l31) * 72 + ks * 16 + l5 * 8];
      sv0 = __builtin_amdgcn_mfma_f32_32x32x16_bf16(kf0, qf[ks], sv0, 0, 0, 0);
      sv1 = __builtin_amdgcn_mfma_f32_32x32x16_bf16(kf1, qf[ks], sv1, 0, 0, 0);
    }
    __builtin_amdgcn_s_setprio(0);

    // online softmax (exp2 domain; scale pre-folded into Q)
    float mx = sv0[0];
#pragma unroll
    for (int i = 0; i < 16; ++i) mx = fmaxf(mx, sv0[i]);
#pragma unroll
    for (int i = 0; i < 16; ++i) mx = fmaxf(mx, sv1[i]);
    {
      const u32 mb = __builtin_bit_cast(u32, mx);
      const u32x2 rr = __builtin_amdgcn_permlane32_swap(mb, mb, false, false);
      mx = fmaxf(__builtin_bit_cast(float, rr[0]), __builtin_bit_cast(float, rr[1]));
    }
    if (!__all(mx - m <= DTHR)) {
      const float mn = fmaxf(m, mx);
      const float al = __builtin_amdgcn_exp2f(m - mn);
      m = mn;
      l *= al;
#pragma unroll
      for (int i = 0; i < 16; ++i) { o0[i] *= al; o1[i] *= al; }
    }
    float rs = 0.f;
#pragma unroll
    for (int i = 0; i < 16; ++i) {
      const float e = __builtin_amdgcn_exp2f(sv0[i] - m);
      sv0[i] = e; rs += e;
    }
#pragma unroll
    for (int i = 0; i < 16; ++i) {
      const float e = __builtin_amdgcn_exp2f(sv1[i] - m);
      sv1[i] = e; rs += e;
    }
    {
      const u32 sb = __builtin_bit_cast(u32, rs);
      const u32x2 rr = __builtin_amdgcn_permlane32_swap(sb, sb, false, false);
      rs = __builtin_bit_cast(float, rr[0]) + __builtin_bit_cast(float, rr[1]);
    }
    l += rs;

    // P -> bf16 B-fragments in-register (T12)
    bf16x8 pb[4];
#pragma unroll
    for (int kb = 0; kb < 2; ++kb) {
      const f32x16& p = kb ? sv1 : sv0;
#pragma unroll
      for (int half = 0; half < 2; ++half) {
        const int o8 = half * 8;
        const u32 a0 = cvt_pk_bf16(p[o8 + 0], p[o8 + 1]);
        const u32 b0 = cvt_pk_bf16(p[o8 + 4], p[o8 + 5]);
        const u32 a1 = cvt_pk_bf16(p[o8 + 2], p[o8 + 3]);
        const u32 b1 = cvt_pk_bf16(p[o8 + 6], p[o8 + 7]);
        const u32x2 r0 = __builtin_amdgcn_permlane32_swap(a0, b0, false, false);
        const u32x2 r1 = __builtin_amdgcn_permlane32_swap(a1, b1, false, false);
        u32 w[4] = { r0[0], r1[0], r0[1], r1[1] };
        pb[kb * 2 + half] = __builtin_bit_cast(bf16x8, *(const uint4*)w);
      }
    }

    // PV
    __builtin_amdgcn_s_setprio(1);
#pragma unroll
    for (int ks2 = 0; ks2 < 4; ++ks2) {
      const bf16x8 vf0 = *(const bf16x8*)&VTs[(l31)      * 72 + ks2 * 16 + l5 * 8];
      const bf16x8 vf1 = *(const bf16x8*)&VTs[(32 + l31) * 72 + ks2 * 16 + l5 * 8];
      o0 = __builtin_amdgcn_mfma_f32_32x32x16_bf16(vf0, pb[ks2], o0, 0, 0, 0);
      o1 = __builtin_amdgcn_mfma_f32_32x32x16_bf16(vf1, pb[ks2], o1, 0, 0, 0);
    }
    __builtin_amdgcn_s_setprio(0);
  }

  // partial epilogue: unnormalized fp32 O + (m, l) per q-row
  float* op = Opart + (((size_t)z * B_N * H_N + bh) * S_N + qrow) * 64;
#pragma unroll
  for (int r = 0; r < 16; r += 2) {
    const int dh = (r & 3) + 8 * (r >> 2) + 4 * l5;
    *(float2*)(op + dh)      = float2{o0[r], o0[r + 1]};
    *(float2*)(op + dh + 32) = float2{o1[r], o1[r + 1]};
  }
  if (l5 == 0) {
    float* mlp = Ml + (((size_t)z * B_N * H_N + bh) * S_N + qrow) * 2;
    mlp[0] = m; mlp[1] = l;
  }
}

// ---------- combine KV-half partials -> ab (bf16, head-interleaved) ----------
__global__ __launch_bounds__(256) void attn_combine_kernel(
    const float* __restrict__ Opart, const float* __restrict__ Ml, u16* __restrict__ O)
{
  constexpr size_t HALF = (size_t)B_N * H_N * S_N;   // rows per z-half
  const int tid = threadIdx.x;
  const int lane = tid & 63, grp = tid >> 6;
  const size_t row = (size_t)blockIdx.x * 4 + grp;   // (b*H + h)*S + s
  const float* p0 = Opart + row * 64;
  const float* p1 = p0 + HALF * 64;
  const float m0 = Ml[row * 2], l0 = Ml[row * 2 + 1];
  const float m1 = Ml[(row + HALF) * 2], l1 = Ml[(row + HALF) * 2 + 1];
  const float mm = fmaxf(m0, m1);
  const float a0 = __builtin_amdgcn_exp2f(m0 - mm);
  const float a1 = __builtin_amdgcn_exp2f(m1 - mm);
  const float inv = 1.f / (a0 * l0 + a1 * l1);
  const float o = (a0 * p0[lane] + a1 * p1[lane]) * inv;
  const int bh = (int)(row / S_N), s = (int)(row % S_N);
  const int b = bh / H_N, h = bh - b * H_N;
  O[((size_t)b * S_N + s) * D_N + h * 64 + lane] = f2bf(o);
}

// ---------- orchestration ----------
extern "C" void kernel_launch(void* const* d_in, const int* in_sizes, int n_in,
                              void* d_out, int out_size, void* d_ws, size_t ws_size,
                              hipStream_t stream)
{
  (void)in_sizes; (void)n_in; (void)out_size; (void)ws_size;
  const float* x0   = (const float*)d_in[0];
  const float* Wq   = (const float*)d_in[1];
  const float* bq   = (const float*)d_in[2];
  const float* Wk   = (const float*)d_in[3];
  const float* bk   = (const float*)d_in[4];
  const float* Wv   = (const float*)d_in[5];
  const float* bv   = (const float*)d_in[6];
  const float* Wo   = (const float*)d_in[7];
  const float* bo   = (const float*)d_in[8];
  const float* ln1w = (const float*)d_in[9];
  const float* ln1b = (const float*)d_in[10];
  const float* W1   = (const float*)d_in[11];
  const float* b1   = (const float*)d_in[12];
  const float* W2   = (const float*)d_in[13];
  const float* b2   = (const float*)d_in[14];
  const float* ln2w = (const float*)d_in[15];
  const float* ln2b = (const float*)d_in[16];
  const float* lnfw = (const float*)d_in[17];
  const float* lnfb = (const float*)d_in[18];

  char* ws = (char*)d_ws;
  size_t off = 0;
  auto alloc = [&](size_t bytes) {
    char* p = ws + off; off += (bytes + 255) & ~(size_t)255; return p;
  };
  u16*   wqkv_t = (u16*)alloc((size_t)L_N * QKV_N * D_N * 2);  // (L, 2304, 768)
  u16*   wo_t   = (u16*)alloc((size_t)L_N * D_N * D_N * 2);
  u16*   w1_t   = (u16*)alloc((size_t)L_N * D_N * F_N * 2);    // (L, 3072, 768)
  u16*   w2_t   = (u16*)alloc((size_t)L_N * D_N * F_N * 2);    // (L, 768, 3072)
  float* bqkv   = (float*)alloc((size_t)L_N * QKV_N * 4);
  u16*   x_b    = (u16*)alloc((size_t)BS_N * D_N * 2);         // bf16 residual stream
  u16*   xn_b   = (u16*)alloc((size_t)BS_N * D_N * 2);
  u16*   qkvb   = (u16*)alloc((size_t)BS_N * QKV_N * 2);
  u16*   ab     = (u16*)alloc((size_t)BS_N * D_N * 2);
  u16*   hb     = (u16*)alloc((size_t)BS_N * F_N * 2);         // 25.2 MB; aliased by Opart
  float* ml     = (float*)alloc((size_t)2 * B_N * H_N * S_N * 2 * 4);
  float* opart  = (float*)hb;   // 2*B*H*S*64 fp32 = 25.2 MB, dead during attention

  const size_t dd = (size_t)D_N * D_N, qs = (size_t)QKV_N * D_N, df = (size_t)D_N * F_N;
  transpose_cast_kernel<<<dim3(D_N/32, D_N/32, L_N), 256, 0, stream>>>(Wq, wqkv_t, D_N, D_N, qs, 0);
  transpose_cast_kernel<<<dim3(D_N/32, D_N/32, L_N), 256, 0, stream>>>(Wk, wqkv_t, D_N, D_N, qs, 768);
  transpose_cast_kernel<<<dim3(D_N/32, D_N/32, L_N), 256, 0, stream>>>(Wv, wqkv_t, D_N, D_N, qs, 1536);
  transpose_cast_kernel<<<dim3(D_N/32, D_N/32, L_N), 256, 0, stream>>>(Wo, wo_t, D_N, D_N, dd, 0);
  transpose_cast_kernel<<<dim3(F_N/32, D_N/32, L_N), 256, 0, stream>>>(W1, w1_t, D_N, F_N, df, 0);
  transpose_cast_kernel<<<dim3(D_N/32, F_N/32, L_N), 256, 0, stream>>>(W2, w2_t, F_N, D_N, df, 0);
  concat_bias_kernel<<<(L_N * QKV_N) / 256, 256, 0, stream>>>(bq, bk, bv, bqkv);

  const dim3 gQKV(BS_N / 128, QKV_N / 96);   // (32, 24) -> 768 blocks, 3/CU balanced
  const dim3 gF  (BS_N / 128, F_N / 128);    // (32, 24) -> 768 blocks, 3/CU
  const dim3 g64 (BS_N / 64,  D_N / 64);     // (64, 12) -> 768 blocks, 3/CU
  const dim3 gA  (S_N / 128, B_N * H_N, 2);  // (16, 24, 2) -> 768 blocks, 3/CU
  const int  gLN = BS_N / 4;                 // 1024 blocks, 4 rows each

  for (int i = 0; i < L_N; ++i) {
    if (i == 0)
      ln_kernel<false><<<gLN, 256, 0, stream>>>(x0, ln1w, ln1b, nullptr, xn_b);
    else
      ln_kernel<true><<<gLN, 256, 0, stream>>>(x_b, ln1w + i * D_N, ln1b + i * D_N, nullptr, xn_b);
    gemm96_kernel<<<gQKV, 256, 0, stream>>>(
        xn_b, wqkv_t + (size_t)i * qs, bqkv + (size_t)i * QKV_N, qkvb, BS_N, QKV_N, D_N);
    attn_kernel<<<gA, 256, 0, stream>>>(qkvb, opart, ml);
    attn_combine_kernel<<<(B_N * H_N * S_N) / 4, 256, 0, stream>>>(opart, ml, ab);
    gemm64_kernel<<<g64, 256, 0, stream>>>(
        ab, wo_t + (size_t)i * dd, bo + i * D_N, xn_b, x_b, BS_N, D_N, D_N);
    ln_kernel<true><<<gLN, 256, 0, stream>>>(x_b, ln2w + i * D_N, ln2b + i * D_N, nullptr, xn_b);
    gemm_kernel<true,true,false><<<gF, 256, 0, stream>>>(
        xn_b, w1_t + (size_t)i * df, b1 + i * F_N, hb, BS_N, F_N, D_N);
    gemm64_kernel<<<g64, 256, 0, stream>>>(
        hb, w2_t + (size_t)i * df, b2 + i * D_N, xn_b, x_b, BS_N, D_N, F_N);
  }
  ln_kernel<true><<<gLN, 256, 0, stream>>>(x_b, lnfw, lnfb, (float*)d_out, nullptr);
}

// Round 17
// 1233.112 us; speedup vs baseline: 1.3521x; 1.0582x over previous
//
#include <hip/hip_runtime.h>
#include <stdint.h>

typedef unsigned short u16;
typedef unsigned int   u32;

#define L_N  6
#define D_N  768
#define F_N  3072
#define H_N  12
#define B_N  2
#define S_N  2048
#define BS_N 4096   // B*S rows
#define QKV_N 2304  // fused q|k|v width
#define CSC  0.18033688011112042f   // 1/sqrt(64) * log2(e), folded into Q
#define DTHR 11.54f                 // 8 * log2(e): defer-max threshold (exp2 domain)

using bf16x8 = __attribute__((ext_vector_type(8))) short;
using f32x4  = __attribute__((ext_vector_type(4))) float;
using f32x16 = __attribute__((ext_vector_type(16))) float;
using u32x2  = __attribute__((ext_vector_type(2))) unsigned int;

__device__ __forceinline__ u16 f2bf(float f) {
  u32 x = __builtin_bit_cast(u32, f);
  x += 0x7FFFu + ((x >> 16) & 1u);
  return (u16)(x >> 16);
}

__device__ __forceinline__ float bf2f(u16 v) {
  return __builtin_bit_cast(float, (u32)v << 16);
}

__device__ __forceinline__ u32 cvt_pk_bf16(float lo, float hi) {
  u32 r;
  asm("v_cvt_pk_bf16_f32 %0, %1, %2" : "=v"(r) : "v"(lo), "v"(hi));
  return r;
}

#define GLOAD16(g, l)                                                                     \
  __builtin_amdgcn_global_load_lds((const __attribute__((address_space(1))) void*)(g),    \
                                   (__attribute__((address_space(3))) void*)(l), 16, 0, 0)

// ---------- transpose + cast: in (L,K,N) f32 -> out rows at (l*lstride + (rowoff+n)*K) bf16 ----------
__global__ __launch_bounds__(256) void transpose_cast_kernel(
    const float* __restrict__ in, u16* __restrict__ out, int K, int N,
    size_t out_lstride, int out_rowoff)
{
  __shared__ float tile[32][33];
  const int l  = blockIdx.z;
  const int n0 = blockIdx.x * 32, k0 = blockIdx.y * 32;
  const int tx = threadIdx.x & 31, ty = threadIdx.x >> 5;
  const float* src = in + (size_t)l * K * N;
  u16* dst = out + (size_t)l * out_lstride + (size_t)out_rowoff * K;
#pragma unroll
  for (int i = 0; i < 4; ++i)
    tile[ty + i * 8][tx] = src[(size_t)(k0 + ty + i * 8) * N + n0 + tx];
  __syncthreads();
#pragma unroll
  for (int i = 0; i < 4; ++i)
    dst[(size_t)(n0 + ty + i * 8) * K + k0 + tx] = f2bf(tile[tx][ty + i * 8]);
}

// ---------- concat q|k|v biases into (L, 2304) ----------
__global__ __launch_bounds__(256) void concat_bias_kernel(
    const float* __restrict__ bq, const float* __restrict__ bk,
    const float* __restrict__ bv, float* __restrict__ out)
{
  const int i = blockIdx.x * 256 + threadIdx.x;   // exact grid: L*2304
  const int l = i / QKV_N, c = i - l * QKV_N;
  float v = (c < 768) ? bq[l * 768 + c]
          : (c < 1536) ? bk[l * 768 + c - 768]
                       : bv[l * 768 + c - 1536];
  out[i] = v;
}

// ---------- LayerNorm v2: wave-per-row, vectorized, zero-LDS ----------
template<bool BF16IN>
__global__ __launch_bounds__(256) void ln_kernel(
    const void* __restrict__ xv, const float* __restrict__ w, const float* __restrict__ b,
    float* __restrict__ outF, u16* __restrict__ outB)
{
  const int wave = threadIdx.x >> 6, lane = threadIdx.x & 63;
  const int row  = blockIdx.x * 4 + wave;
  const int c0 = lane * 8, c1 = 512 + lane * 4;   // bf16-path cols
  float v[12], wv[12], bv[12];

  if (BF16IN) {
    const u16* xr = (const u16*)xv + (size_t)row * D_N;
    const uint4 a  = *(const uint4*)(xr + c0);
    const uint2 a2 = *(const uint2*)(xr + c1);
    const u16* pa = (const u16*)&a;
#pragma unroll
    for (int i = 0; i < 8; ++i) v[i] = bf2f(pa[i]);
    const u16* pb = (const u16*)&a2;
#pragma unroll
    for (int i = 0; i < 4; ++i) v[8 + i] = bf2f(pb[i]);
    *(float4*)&wv[0] = *(const float4*)(w + c0);
    *(float4*)&wv[4] = *(const float4*)(w + c0 + 4);
    *(float4*)&wv[8] = *(const float4*)(w + c1);
    *(float4*)&bv[0] = *(const float4*)(b + c0);
    *(float4*)&bv[4] = *(const float4*)(b + c0 + 4);
    *(float4*)&bv[8] = *(const float4*)(b + c1);
  } else {
    const float* xr = (const float*)xv + (size_t)row * D_N;
#pragma unroll
    for (int r = 0; r < 3; ++r) {
      *(float4*)&v[r * 4]  = *(const float4*)(xr + r * 256 + lane * 4);
      *(float4*)&wv[r * 4] = *(const float4*)(w + r * 256 + lane * 4);
      *(float4*)&bv[r * 4] = *(const float4*)(b + r * 256 + lane * 4);
    }
  }

  float s = 0.f;
#pragma unroll
  for (int i = 0; i < 12; ++i) s += v[i];
#pragma unroll
  for (int o = 32; o > 0; o >>= 1) s += __shfl_xor(s, o, 64);
  const float mu = s * (1.f / D_N);
  float d2 = 0.f;
#pragma unroll
  for (int i = 0; i < 12; ++i) { const float d = v[i] - mu; d2 += d * d; }
#pragma unroll
  for (int o = 32; o > 0; o >>= 1) d2 += __shfl_xor(d2, o, 64);
  const float rs = rsqrtf(d2 * (1.f / D_N) + 1e-5f);

  float o[12];
#pragma unroll
  for (int i = 0; i < 12; ++i) o[i] = (v[i] - mu) * rs * wv[i] + bv[i];

  if (BF16IN) {
    if (outB) {
      u16* orow = outB + (size_t)row * D_N;
      u32 pk[4];
#pragma unroll
      for (int i = 0; i < 4; ++i) pk[i] = cvt_pk_bf16(o[2 * i], o[2 * i + 1]);
      *(uint4*)(orow + c0) = *(const uint4*)pk;
      u32 pk2[2] = { cvt_pk_bf16(o[8], o[9]), cvt_pk_bf16(o[10], o[11]) };
      *(uint2*)(orow + c1) = *(const uint2*)pk2;
    }
    if (outF) {
      float* frow = outF + (size_t)row * D_N;
      *(float4*)(frow + c0)     = *(const float4*)&o[0];
      *(float4*)(frow + c0 + 4) = *(const float4*)&o[4];
      *(float4*)(frow + c1)     = *(const float4*)&o[8];
    }
  } else {
    if (outB) {
      u16* orow = outB + (size_t)row * D_N;
#pragma unroll
      for (int r = 0; r < 3; ++r) {
        u32 pk2[2] = { cvt_pk_bf16(o[r * 4], o[r * 4 + 1]),
                       cvt_pk_bf16(o[r * 4 + 2], o[r * 4 + 3]) };
        *(uint2*)(orow + r * 256 + lane * 4) = *(const uint2*)pk2;
      }
    }
    if (outF) {
      float* frow = outF + (size_t)row * D_N;
#pragma unroll
      for (int r = 0; r < 3; ++r)
        *(float4*)(frow + r * 256 + lane * 4) = *(const float4*)&o[r * 4];
    }
  }
}

// ---------- GEMM 128x128: C = A @ Wt^T + bias, fused epilogue (W1) ----------
template<bool GELU, bool OUTB, bool SCALEQ>
__global__ __launch_bounds__(256) void gemm_kernel(
    const u16* __restrict__ A, const u16* __restrict__ Wt,
    const float* __restrict__ bias,
    u16* __restrict__ outB, int M, int N, int K)
{
  __shared__ __align__(16) u16 As[2][128 * 32];
  __shared__ __align__(16) u16 Bs[2][128 * 32];
  const int tid  = threadIdx.x;
  const int wave = tid >> 6, lane = tid & 63;
  const int lr = lane & 15, lg = lane >> 4;
  const int row0 = blockIdx.x * 128, col0 = blockIdx.y * 128;
  const int wr = (wave >> 1) * 64, wc = (wave & 1) * 64;

  const int cb0 = wave * 64;
  const int cb1 = 256 + wave * 64;
  const int r0s = (cb0 + lane) >> 2, c0s = ((cb0 + lane) & 3) << 3;
  const int r1s = (cb1 + lane) >> 2, c1s = ((cb1 + lane) & 3) << 3;

  f32x4 acc[4][4] = {};

#define STAGE(cbuf, kk)                                                           \
  do {                                                                            \
    GLOAD16(A  + (size_t)(row0 + r0s) * K + (kk) + c0s, &As[cbuf][cb0 * 8]);      \
    GLOAD16(Wt + (size_t)(col0 + r0s) * K + (kk) + c0s, &Bs[cbuf][cb0 * 8]);      \
    GLOAD16(A  + (size_t)(row0 + r1s) * K + (kk) + c1s, &As[cbuf][cb1 * 8]);      \
    GLOAD16(Wt + (size_t)(col0 + r1s) * K + (kk) + c1s, &Bs[cbuf][cb1 * 8]);      \
  } while (0)

  STAGE(0, 0);
  __syncthreads();

  int c = 0;
  for (int k0 = 0; k0 < K; k0 += 32, c ^= 1) {
    if (k0 + 32 < K) STAGE(c ^ 1, k0 + 32);
    bf16x8 af[4], bfr[4];
#pragma unroll
    for (int m = 0; m < 4; ++m)
      af[m] = *(const bf16x8*)&As[c][(wr + m * 16 + lr) * 32 + lg * 8];
#pragma unroll
    for (int n = 0; n < 4; ++n)
      bfr[n] = *(const bf16x8*)&Bs[c][(wc + n * 16 + lr) * 32 + lg * 8];
    __builtin_amdgcn_s_setprio(1);
#pragma unroll
    for (int m = 0; m < 4; ++m)
#pragma unroll
      for (int n = 0; n < 4; ++n)
        acc[m][n] = __builtin_amdgcn_mfma_f32_16x16x32_bf16(af[m], bfr[n], acc[m][n], 0, 0, 0);
    __builtin_amdgcn_s_setprio(0);
    __syncthreads();
  }
#undef STAGE

#pragma unroll
  for (int m = 0; m < 4; ++m)
#pragma unroll
    for (int n = 0; n < 4; ++n) {
      const int col = col0 + wc + n * 16 + lr;
      const float bv = bias[col];
#pragma unroll
      for (int r = 0; r < 4; ++r) {
        const int row = row0 + wr + m * 16 + lg * 4 + r;
        float v = acc[m][n][r] + bv;
        if (GELU) v = 0.5f * v * (1.f + erff(v * 0.70710678118f));
        if (SCALEQ && col < 768) v *= CSC;
        const size_t idx = (size_t)row * N + col;
        if (OUTB) outB[idx] = f2bf(v);
      }
    }
}

// ---------- GEMM 128x96 (QKV): 768 blocks = 3/CU balanced; +bias, SCALEQ, bf16 out ----------
__global__ __launch_bounds__(256) void gemm96_kernel(
    const u16* __restrict__ A, const u16* __restrict__ Wt,
    const float* __restrict__ bias, u16* __restrict__ outB,
    int M, int N, int K)
{
  __shared__ __align__(16) u16 As[2][128 * 32];   // 8 KB each
  __shared__ __align__(16) u16 Bs[2][96 * 32];    // 6 KB each
  const int tid  = threadIdx.x;
  const int wave = tid >> 6, lane = tid & 63;
  const int lr = lane & 15, lg = lane >> 4;
  const int row0 = blockIdx.x * 128, col0 = blockIdx.y * 96;
  const int wr = (wave >> 1) * 64, wc = (wave & 1) * 48;

  const int cb0 = wave * 64;            // chunks 0..255   (A it0 / B rows 0..63)
  const int cb1 = 256 + wave * 64;      // chunks 256..511 (A it1; B rows 64..95 for wave<2)
  const int r0s = (cb0 + lane) >> 2, c0s = ((cb0 + lane) & 3) << 3;
  const int r1s = (cb1 + lane) >> 2, c1s = ((cb1 + lane) & 3) << 3;

  f32x4 acc[4][3] = {};

#define STAGE96(cbuf, kk)                                                         \
  do {                                                                            \
    GLOAD16(A  + (size_t)(row0 + r0s) * K + (kk) + c0s, &As[cbuf][cb0 * 8]);      \
    GLOAD16(A  + (size_t)(row0 + r1s) * K + (kk) + c1s, &As[cbuf][cb1 * 8]);      \
    GLOAD16(Wt + (size_t)(col0 + r0s) * K + (kk) + c0s, &Bs[cbuf][cb0 * 8]);      \
    if (wave < 2)                                                                 \
      GLOAD16(Wt + (size_t)(col0 + r1s) * K + (kk) + c1s, &Bs[cbuf][cb1 * 8]);    \
  } while (0)

  STAGE96(0, 0);
  __syncthreads();

  int c = 0;
  for (int k0 = 0; k0 < K; k0 += 32, c ^= 1) {
    if (k0 + 32 < K) STAGE96(c ^ 1, k0 + 32);
    bf16x8 af[4], bfr[3];
#pragma unroll
    for (int m = 0; m < 4; ++m)
      af[m] = *(const bf16x8*)&As[c][(wr + m * 16 + lr) * 32 + lg * 8];
#pragma unroll
    for (int n = 0; n < 3; ++n)
      bfr[n] = *(const bf16x8*)&Bs[c][(wc + n * 16 + lr) * 32 + lg * 8];
    __builtin_amdgcn_s_setprio(1);
#pragma unroll
    for (int m = 0; m < 4; ++m)
#pragma unroll
      for (int n = 0; n < 3; ++n)
        acc[m][n] = __builtin_amdgcn_mfma_f32_16x16x32_bf16(af[m], bfr[n], acc[m][n], 0, 0, 0);
    __builtin_amdgcn_s_setprio(0);
    __syncthreads();
  }
#undef STAGE96

#pragma unroll
  for (int m = 0; m < 4; ++m)
#pragma unroll
    for (int n = 0; n < 3; ++n) {
      const int col = col0 + wc + n * 16 + lr;
      const float bv = bias[col];
#pragma unroll
      for (int r = 0; r < 4; ++r) {
        const int row = row0 + wr + m * 16 + lg * 4 + r;
        float v = acc[m][n][r] + bv;
        if (col < 768) v *= CSC;   // fold softmax scale into q
        outB[(size_t)row * N + col] = f2bf(v);
      }
    }
}

// ---------- GEMM 64x64 BK=64 (Wo, W2): +bias +bf16resid -> bf16 out ----------
// LDS per buffer = two 64x32 k-subtiles (linear gload_lds dests, proven
// stride-32 fragment reads). 8 MFMA per 2-barrier step; barrier count halved.
__global__ __launch_bounds__(256) void gemm64_kernel(
    const u16* __restrict__ A, const u16* __restrict__ Wt,
    const float* __restrict__ bias, const u16* __restrict__ resid,
    u16* __restrict__ outB, int M, int N, int K)
{
  __shared__ __align__(16) u16 As[2][2 * 64 * 32];   // [buf][subtile k0/k1][64][32]
  __shared__ __align__(16) u16 Bs[2][2 * 64 * 32];
  const int tid  = threadIdx.x;
  const int wave = tid >> 6, lane = tid & 63;
  const int lr = lane & 15, lg = lane >> 4;
  const int row0 = blockIdx.x * 64, col0 = blockIdx.y * 64;
  const int wr = (wave >> 1) * 32, wc = (wave & 1) * 32;

  // staging: thread handles row rs, cols cs0 (subtile 0) and cs0+32 (subtile 1)
  const int cb = wave * 64;                       // wave-uniform chunk base
  const int rs = tid >> 2, cs0 = (tid & 3) << 3;

  f32x4 acc[2][2] = {};

#define STAGE64(cbuf, kk)                                                             \
  do {                                                                               \
    GLOAD16(A  + (size_t)(row0 + rs) * K + (kk) + cs0,      &As[cbuf][cb * 8]);       \
    GLOAD16(A  + (size_t)(row0 + rs) * K + (kk) + cs0 + 32, &As[cbuf][2048 + cb * 8]);\
    GLOAD16(Wt + (size_t)(col0 + rs) * K + (kk) + cs0,      &Bs[cbuf][cb * 8]);       \
    GLOAD16(Wt + (size_t)(col0 + rs) * K + (kk) + cs0 + 32, &Bs[cbuf][2048 + cb * 8]);\
  } while (0)

  STAGE64(0, 0);
  __syncthreads();

  int c = 0;
  for (int k0 = 0; k0 < K; k0 += 64, c ^= 1) {
    if (k0 + 64 < K) STAGE64(c ^ 1, k0 + 64);
#pragma unroll
    for (int kk2 = 0; kk2 < 2; ++kk2) {
      const int sb = kk2 * 2048;
      bf16x8 af[2], bfr[2];
#pragma unroll
      for (int m = 0; m < 2; ++m)
        af[m] = *(const bf16x8*)&As[c][sb + (wr + m * 16 + lr) * 32 + lg * 8];
#pragma unroll
      for (int n = 0; n < 2; ++n)
        bfr[n] = *(const bf16x8*)&Bs[c][sb + (wc + n * 16 + lr) * 32 + lg * 8];
      __builtin_amdgcn_s_setprio(1);
#pragma unroll
      for (int m = 0; m < 2; ++m)
#pragma unroll
        for (int n = 0; n < 2; ++n)
          acc[m][n] = __builtin_amdgcn_mfma_f32_16x16x32_bf16(af[m], bfr[n], acc[m][n], 0, 0, 0);
      __builtin_amdgcn_s_setprio(0);
    }
    __syncthreads();
  }
#undef STAGE64

#pragma unroll
  for (int m = 0; m < 2; ++m)
#pragma unroll
    for (int n = 0; n < 2; ++n) {
      const int col = col0 + wc + n * 16 + lr;
      const float bv = bias[col];
#pragma unroll
      for (int r = 0; r < 4; ++r) {
        const int row = row0 + wr + m * 16 + lg * 4 + r;
        const size_t idx = (size_t)row * N + col;
        outB[idx] = f2bf(acc[m][n][r] + bv + bf2f(resid[idx]));
      }
    }
}

// ---------- Flash attention v12 (round-12 best): v9 + split-KV x2 ----------
__global__ __launch_bounds__(256) void attn_kernel(
    const u16* __restrict__ QKV, float* __restrict__ Opart, float* __restrict__ Ml)
{
  constexpr int LDQ = QKV_N;
  constexpr int NT  = S_N / 64;   // 32
  __shared__ __align__(16) u16 Ks [64 * 72];   // [key][dh]
  __shared__ __align__(16) u16 VTs[64 * 72];   // [dh][key]
  const int tid  = threadIdx.x;
  const int wave = tid >> 6, lane = tid & 63;
  const int l31 = lane & 31, l5 = lane >> 5;
  const int bh = blockIdx.y;
  const int b = bh / H_N, h = bh - b * H_N;
  const int q0 = blockIdx.x * 128;
  const int z  = blockIdx.z;
  const int t0 = z * (NT / 2), t1 = (z + 1) * (NT / 2);
  const size_t rowbase = (size_t)b * S_N * LDQ;
  const u16* Qg = QKV + rowbase + h * 64;
  const u16* Kg = QKV + rowbase + 768 + h * 64;
  const u16* Vg = QKV + rowbase + 1536 + h * 64;

  const int qrow = q0 + wave * 32 + l31;
  bf16x8 qf[4];
#pragma unroll
  for (int ks = 0; ks < 4; ++ks)
    qf[ks] = *(const bf16x8*)(Qg + (size_t)qrow * LDQ + ks * 16 + l5 * 8);

  f32x16 o0 = {}, o1 = {};
  float m = -1e30f, l = 0.f;

  const int kr = tid >> 2, kc = (tid & 3) * 16;   // K staging coords
  const int pp = tid >> 3, cg = tid & 7;          // V staging coords

  const u16* gk0 = Kg + (size_t)(t0 * 64 + kr) * LDQ + kc;
  const u16* gv0 = Vg + (size_t)(t0 * 64 + 2 * pp) * LDQ + cg * 8;
  uint4 nk0 = *(const uint4*)gk0, nk1 = *(const uint4*)(gk0 + 8);
  uint4 nv0 = *(const uint4*)gv0, nv1 = *(const uint4*)(gv0 + LDQ);

  for (int t = t0; t < t1; ++t) {
    __syncthreads();
    { // LDS writes of tile t (K row-major; V transposed, jj-rotated u32 pairs)
      *(uint4*)&Ks[kr * 72 + kc]     = nk0;
      *(uint4*)&Ks[kr * 72 + kc + 8] = nk1;
      const u16* a0 = (const u16*)&nv0;
      const u16* a1 = (const u16*)&nv1;
#pragma unroll
      for (int j = 0; j < 8; ++j) {
        const int jj = (j + cg) & 7;
        *(u32*)&VTs[(cg * 8 + jj) * 72 + 2 * pp] = (u32)a0[jj] | ((u32)a1[jj] << 16);
      }
    }
    __syncthreads();

    if (t + 1 < t1) {
      const u16* gk1 = Kg + (size_t)((t + 1) * 64 + kr) * LDQ + kc;
      const u16* gv1 = Vg + (size_t)((t + 1) * 64 + 2 * pp) * LDQ + cg * 8;
      nk0 = *(const uint4*)gk1; nk1 = *(const uint4*)(gk1 + 8);
      nv0 = *(const uint4*)gv1; nv1 = *(const uint4*)(gv1 + LDQ);
    }

    // S^T = K @ Q^T: sv0/sv1 cover keys 0..31 / 32..63 x q=l31
    f32x16 sv0 = {}, sv1 = {};
    __builtin_amdgcn_s_setprio(1);
#pragma unroll
    for (int ks = 0; ks < 4; ++ks) {
      const bf16x8 kf0 = *(const bf16x8*)&Ks[(l31)      * 72 + ks * 16 + l5 * 8];
      const bf16x8 kf1 = *(const bf16x8*)&Ks[(32 + l31) * 72 + ks * 16 + l5 * 8];
      sv0 = __builtin_amdgcn_mfma_f32_32x32x16_bf16(kf0, qf[ks], sv0, 0, 0, 0);
      sv1 = __builtin_amdgcn_mfma_f32_32x32x16_bf16(kf1, qf[ks], sv1, 0, 0, 0);
    }
    __builtin_amdgcn_s_setprio(0);

    // online softmax (exp2 domain; scale pre-folded into Q)
    float mx = sv0[0];
#pragma unroll
    for (int i = 0; i < 16; ++i) mx = fmaxf(mx, sv0[i]);
#pragma unroll
    for (int i = 0; i < 16; ++i) mx = fmaxf(mx, sv1[i]);
    {
      const u32 mb = __builtin_bit_cast(u32, mx);
      const u32x2 rr = __builtin_amdgcn_permlane32_swap(mb, mb, false, false);
      mx = fmaxf(__builtin_bit_cast(float, rr[0]), __builtin_bit_cast(float, rr[1]));
    }
    if (!__all(mx - m <= DTHR)) {
      const float mn = fmaxf(m, mx);
      const float al = __builtin_amdgcn_exp2f(m - mn);
      m = mn;
      l *= al;
#pragma unroll
      for (int i = 0; i < 16; ++i) { o0[i] *= al; o1[i] *= al; }
    }
    float rs = 0.f;
#pragma unroll
    for (int i = 0; i < 16; ++i) {
      const float e = __builtin_amdgcn_exp2f(sv0[i] - m);
      sv0[i] = e; rs += e;
    }
#pragma unroll
    for (int i = 0; i < 16; ++i) {
      const float e = __builtin_amdgcn_exp2f(sv1[i] - m);
      sv1[i] = e; rs += e;
    }
    {
      const u32 sb = __builtin_bit_cast(u32, rs);
      const u32x2 rr = __builtin_amdgcn_permlane32_swap(sb, sb, false, false);
      rs = __builtin_bit_cast(float, rr[0]) + __builtin_bit_cast(float, rr[1]);
    }
    l += rs;

    // P -> bf16 B-fragments in-register (T12)
    bf16x8 pb[4];
#pragma unroll
    for (int kb = 0; kb < 2; ++kb) {
      const f32x16& p = kb ? sv1 : sv0;
#pragma unroll
      for (int half = 0; half < 2; ++half) {
        const int o8 = half * 8;
        const u32 a0 = cvt_pk_bf16(p[o8 + 0], p[o8 + 1]);
        const u32 b0 = cvt_pk_bf16(p[o8 + 4], p[o8 + 5]);
        const u32 a1 = cvt_pk_bf16(p[o8 + 2], p[o8 + 3]);
        const u32 b1 = cvt_pk_bf16(p[o8 + 6], p[o8 + 7]);
        const u32x2 r0 = __builtin_amdgcn_permlane32_swap(a0, b0, false, false);
        const u32x2 r1 = __builtin_amdgcn_permlane32_swap(a1, b1, false, false);
        u32 w[4] = { r0[0], r1[0], r0[1], r1[1] };
        pb[kb * 2 + half] = __builtin_bit_cast(bf16x8, *(const uint4*)w);
      }
    }

    // PV
    __builtin_amdgcn_s_setprio(1);
#pragma unroll
    for (int ks2 = 0; ks2 < 4; ++ks2) {
      const bf16x8 vf0 = *(const bf16x8*)&VTs[(l31)      * 72 + ks2 * 16 + l5 * 8];
      const bf16x8 vf1 = *(const bf16x8*)&VTs[(32 + l31) * 72 + ks2 * 16 + l5 * 8];
      o0 = __builtin_amdgcn_mfma_f32_32x32x16_bf16(vf0, pb[ks2], o0, 0, 0, 0);
      o1 = __builtin_amdgcn_mfma_f32_32x32x16_bf16(vf1, pb[ks2], o1, 0, 0, 0);
    }
    __builtin_amdgcn_s_setprio(0);
  }

  // partial epilogue: unnormalized fp32 O + (m, l) per q-row
  float* op = Opart + (((size_t)z * B_N * H_N + bh) * S_N + qrow) * 64;
#pragma unroll
  for (int r = 0; r < 16; r += 2) {
    const int dh = (r & 3) + 8 * (r >> 2) + 4 * l5;
    *(float2*)(op + dh)      = float2{o0[r], o0[r + 1]};
    *(float2*)(op + dh + 32) = float2{o1[r], o1[r + 1]};
  }
  if (l5 == 0) {
    float* mlp = Ml + (((size_t)z * B_N * H_N + bh) * S_N + qrow) * 2;
    mlp[0] = m; mlp[1] = l;
  }
}

// ---------- combine KV-half partials -> ab (bf16, head-interleaved) ----------
__global__ __launch_bounds__(256) void attn_combine_kernel(
    const float* __restrict__ Opart, const float* __restrict__ Ml, u16* __restrict__ O)
{
  constexpr size_t HALF = (size_t)B_N * H_N * S_N;   // rows per z-half
  const int tid = threadIdx.x;
  const int lane = tid & 63, grp = tid >> 6;
  const size_t row = (size_t)blockIdx.x * 4 + grp;   // (b*H + h)*S + s
  const float* p0 = Opart + row * 64;
  const float* p1 = p0 + HALF * 64;
  const float m0 = Ml[row * 2], l0 = Ml[row * 2 + 1];
  const float m1 = Ml[(row + HALF) * 2], l1 = Ml[(row + HALF) * 2 + 1];
  const float mm = fmaxf(m0, m1);
  const float a0 = __builtin_amdgcn_exp2f(m0 - mm);
  const float a1 = __builtin_amdgcn_exp2f(m1 - mm);
  const float inv = 1.f / (a0 * l0 + a1 * l1);
  const float o = (a0 * p0[lane] + a1 * p1[lane]) * inv;
  const int bh = (int)(row / S_N), s = (int)(row % S_N);
  const int b = bh / H_N, h = bh - b * H_N;
  O[((size_t)b * S_N + s) * D_N + h * 64 + lane] = f2bf(o);
}

// ---------- orchestration ----------
extern "C" void kernel_launch(void* const* d_in, const int* in_sizes, int n_in,
                              void* d_out, int out_size, void* d_ws, size_t ws_size,
                              hipStream_t stream)
{
  (void)in_sizes; (void)n_in; (void)out_size; (void)ws_size;
  const float* x0   = (const float*)d_in[0];
  const float* Wq   = (const float*)d_in[1];
  const float* bq   = (const float*)d_in[2];
  const float* Wk   = (const float*)d_in[3];
  const float* bk   = (const float*)d_in[4];
  const float* Wv   = (const float*)d_in[5];
  const float* bv   = (const float*)d_in[6];
  const float* Wo   = (const float*)d_in[7];
  const float* bo   = (const float*)d_in[8];
  const float* ln1w = (const float*)d_in[9];
  const float* ln1b = (const float*)d_in[10];
  const float* W1   = (const float*)d_in[11];
  const float* b1   = (const float*)d_in[12];
  const float* W2   = (const float*)d_in[13];
  const float* b2   = (const float*)d_in[14];
  const float* ln2w = (const float*)d_in[15];
  const float* ln2b = (const float*)d_in[16];
  const float* lnfw = (const float*)d_in[17];
  const float* lnfb = (const float*)d_in[18];

  char* ws = (char*)d_ws;
  size_t off = 0;
  auto alloc = [&](size_t bytes) {
    char* p = ws + off; off += (bytes + 255) & ~(size_t)255; return p;
  };
  u16*   wqkv_t = (u16*)alloc((size_t)L_N * QKV_N * D_N * 2);  // (L, 2304, 768)
  u16*   wo_t   = (u16*)alloc((size_t)L_N * D_N * D_N * 2);
  u16*   w1_t   = (u16*)alloc((size_t)L_N * D_N * F_N * 2);    // (L, 3072, 768)
  u16*   w2_t   = (u16*)alloc((size_t)L_N * D_N * F_N * 2);    // (L, 768, 3072)
  float* bqkv   = (float*)alloc((size_t)L_N * QKV_N * 4);
  u16*   x_b    = (u16*)alloc((size_t)BS_N * D_N * 2);         // bf16 residual stream
  u16*   xn_b   = (u16*)alloc((size_t)BS_N * D_N * 2);
  u16*   qkvb   = (u16*)alloc((size_t)BS_N * QKV_N * 2);
  u16*   ab     = (u16*)alloc((size_t)BS_N * D_N * 2);
  u16*   hb     = (u16*)alloc((size_t)BS_N * F_N * 2);         // 25.2 MB; aliased by Opart
  float* ml     = (float*)alloc((size_t)2 * B_N * H_N * S_N * 2 * 4);
  float* opart  = (float*)hb;   // 2*B*H*S*64 fp32 = 25.2 MB, dead during attention

  const size_t dd = (size_t)D_N * D_N, qs = (size_t)QKV_N * D_N, df = (size_t)D_N * F_N;
  transpose_cast_kernel<<<dim3(D_N/32, D_N/32, L_N), 256, 0, stream>>>(Wq, wqkv_t, D_N, D_N, qs, 0);
  transpose_cast_kernel<<<dim3(D_N/32, D_N/32, L_N), 256, 0, stream>>>(Wk, wqkv_t, D_N, D_N, qs, 768);
  transpose_cast_kernel<<<dim3(D_N/32, D_N/32, L_N), 256, 0, stream>>>(Wv, wqkv_t, D_N, D_N, qs, 1536);
  transpose_cast_kernel<<<dim3(D_N/32, D_N/32, L_N), 256, 0, stream>>>(Wo, wo_t, D_N, D_N, dd, 0);
  transpose_cast_kernel<<<dim3(F_N/32, D_N/32, L_N), 256, 0, stream>>>(W1, w1_t, D_N, F_N, df, 0);
  transpose_cast_kernel<<<dim3(D_N/32, F_N/32, L_N), 256, 0, stream>>>(W2, w2_t, F_N, D_N, df, 0);
  concat_bias_kernel<<<(L_N * QKV_N) / 256, 256, 0, stream>>>(bq, bk, bv, bqkv);

  const dim3 gQKV(BS_N / 128, QKV_N / 96);   // (32, 24) -> 768 blocks, 3/CU balanced
  const dim3 gF  (BS_N / 128, F_N / 128);    // (32, 24) -> 768 blocks, 3/CU
  const dim3 g64 (BS_N / 64,  D_N / 64);     // (64, 12) -> 768 blocks, 3/CU
  const dim3 gA  (S_N / 128, B_N * H_N, 2);  // (16, 24, 2) -> 768 blocks, 3/CU
  const int  gLN = BS_N / 4;                 // 1024 blocks, 4 rows each

  for (int i = 0; i < L_N; ++i) {
    if (i == 0)
      ln_kernel<false><<<gLN, 256, 0, stream>>>(x0, ln1w, ln1b, nullptr, xn_b);
    else
      ln_kernel<true><<<gLN, 256, 0, stream>>>(x_b, ln1w + i * D_N, ln1b + i * D_N, nullptr, xn_b);
    gemm96_kernel<<<gQKV, 256, 0, stream>>>(
        xn_b, wqkv_t + (size_t)i * qs, bqkv + (size_t)i * QKV_N, qkvb, BS_N, QKV_N, D_N);
    attn_kernel<<<gA, 256, 0, stream>>>(qkvb, opart, ml);
    attn_combine_kernel<<<(B_N * H_N * S_N) / 4, 256, 0, stream>>>(opart, ml, ab);
    gemm64_kernel<<<g64, 256, 0, stream>>>(
        ab, wo_t + (size_t)i * dd, bo + i * D_N, xn_b, x_b, BS_N, D_N, D_N);
    ln_kernel<true><<<gLN, 256, 0, stream>>>(x_b, ln2w + i * D_N, ln2b + i * D_N, nullptr, xn_b);
    gemm_kernel<true,true,false><<<gF, 256, 0, stream>>>(
        xn_b, w1_t + (size_t)i * df, b1 + i * F_N, hb, BS_N, F_N, D_N);
    gemm64_kernel<<<g64, 256, 0, stream>>>(
        hb, w2_t + (size_t)i * df, b2 + i * D_N, xn_b, x_b, BS_N, D_N, F_N);
  }
  ln_kernel<true><<<gLN, 256, 0, stream>>>(x_b, lnfw, lnfb, (float*)d_out, nullptr);
}